// Round 14
// baseline (519.798 us; speedup 1.0000x reference)
//
#include <hip/hip_runtime.h>
#include <stdint.h>

#define D_MODEL 1024
#define N_EXP   8
#define HIDDEN  2048
#define TOPK    2

#define BK    64
#define PADM  128
#define NT1   (D_MODEL / BK)   // 16
#define NT2   (HIDDEN / BK)    // 32
#define G1X   1152             // 72 m-tiles(128) x 16 n-tiles(128 h-cols)
#define G2X   288              // 72 m-tiles(128) x 4 n-tiles(256)

typedef short bf16x8 __attribute__((ext_vector_type(8)));
typedef float f32x4 __attribute__((ext_vector_type(4)));

__device__ __forceinline__ unsigned short f2bf(float f) {
    union { float f; unsigned u; } v; v.f = f;
    unsigned r = v.u + 0x7fffu + ((v.u >> 16) & 1u);
    return (unsigned short)(r >> 16);
}

__device__ __forceinline__ float bf2f(unsigned short u) {
    union { unsigned u; float f; } v; v.u = (unsigned)u << 16; return v.f;
}

// pack two f32 -> u32 of 2 bf16 (RNE); low16 = src0
__device__ __forceinline__ unsigned cvtpk(float a, float b) {
    unsigned r;
    asm("v_cvt_pk_bf16_f32 %0, %1, %2" : "=v"(r) : "v"(a), "v"(b));
    return r;
}

__device__ __forceinline__ void gload_lds16(const void* g, void* l) {
    __builtin_amdgcn_global_load_lds(
        (const __attribute__((address_space(1))) void*)g,
        (__attribute__((address_space(3))) void*)l, 16, 0, 0);
}

// ---------------- router + x->bf16 convert ----------------
__global__ __launch_bounds__(256) void k_pre(
    const float* __restrict__ x, const float* __restrict__ wr,
    unsigned short* __restrict__ xb,
    int* __restrict__ tok_e, float* __restrict__ tok_w,
    int* __restrict__ counts, int T)
{
    int t = blockIdx.x * 4 + (threadIdx.x >> 6);
    int lane = threadIdx.x & 63;
    if (t >= T) return;
    const float4* xr = (const float4*)(x + (size_t)t * D_MODEL);
    float acc[N_EXP];
#pragma unroll
    for (int e = 0; e < N_EXP; ++e) acc[e] = 0.f;
#pragma unroll
    for (int j = 0; j < 4; ++j) {
        int c = j * 64 + lane;
        float4 v = xr[c];
        ushort4 pk;
        pk.x = f2bf(v.x); pk.y = f2bf(v.y); pk.z = f2bf(v.z); pk.w = f2bf(v.w);
        *(ushort4*)(xb + (size_t)t * D_MODEL + c * 4) = pk;
        const float4* w4 = (const float4*)(wr + (size_t)c * 4 * N_EXP);
#pragma unroll
        for (int k = 0; k < 4; ++k) {
            float xv = (k == 0) ? v.x : (k == 1) ? v.y : (k == 2) ? v.z : v.w;
            float4 wa = w4[k * 2], wb = w4[k * 2 + 1];
            acc[0] += xv * wa.x; acc[1] += xv * wa.y; acc[2] += xv * wa.z; acc[3] += xv * wa.w;
            acc[4] += xv * wb.x; acc[5] += xv * wb.y; acc[6] += xv * wb.z; acc[7] += xv * wb.w;
        }
    }
#pragma unroll
    for (int off = 32; off > 0; off >>= 1) {
#pragma unroll
        for (int e = 0; e < N_EXP; ++e) acc[e] += __shfl_down(acc[e], off, 64);
    }
    if (lane == 0) {
        float mx = acc[0];
#pragma unroll
        for (int e = 1; e < N_EXP; ++e) mx = fmaxf(mx, acc[e]);
        float p[N_EXP], den = 0.f;
#pragma unroll
        for (int e = 0; e < N_EXP; ++e) { p[e] = __expf(acc[e] - mx); den += p[e]; }
        float inv = 1.f / den;
        int e0 = 0; float v0 = acc[0];
#pragma unroll
        for (int e = 1; e < N_EXP; ++e) if (acc[e] > v0) { v0 = acc[e]; e0 = e; }
        int e1 = -1; float v1 = -1e30f;
#pragma unroll
        for (int e = 0; e < N_EXP; ++e) if (e != e0 && acc[e] > v1) { v1 = acc[e]; e1 = e; }
        tok_e[2 * t] = e0;     tok_w[2 * t] = p[e0] * inv;
        tok_e[2 * t + 1] = e1; tok_w[2 * t + 1] = p[e1] * inv;
        atomicAdd(&counts[e0], 1);
        atomicAdd(&counts[e1], 1);
    }
}

// ---------------- scan (padded to PADM) + scatter, single block ----------------
__global__ void k_scan_scatter(const int* __restrict__ counts,
                               const int* __restrict__ tok_e, const float* __restrict__ tok_w,
                               int* __restrict__ offs,
                               int* __restrict__ row_token, float* __restrict__ row_weight,
                               int* __restrict__ tok_pos, int T) {
    __shared__ int scurs[N_EXP];
    if (threadIdx.x == 0) {
        int s = 0;
        for (int e = 0; e < N_EXP; ++e) {
            offs[e] = s; scurs[e] = s;
            s += ((counts[e] + PADM - 1) / PADM) * PADM;
        }
        offs[N_EXP] = s;
    }
    __syncthreads();
    for (int i = threadIdx.x; i < 2 * T; i += blockDim.x) {
        int e = tok_e[i];
        int pos = atomicAdd(&scurs[e], 1);
        row_token[pos] = i >> 1;
        row_weight[pos] = tok_w[i];
        tok_pos[i] = pos;
    }
}

// ---------------- GEMM1: direct-f32 B staging (no transpose), 128m x 128n(h) ----------------
__global__ __launch_bounds__(512, 1) void k_gemm1(
    const unsigned short* __restrict__ xb,    // [T][D] bf16
    const float* __restrict__ w1,             // [E][D][H] f32
    const float* __restrict__ w3,             // [E][D][H] f32
    const int* __restrict__ row_token,
    const float* __restrict__ row_weight,
    const int* __restrict__ offs,             // [E+1] 128-padded
    unsigned short* __restrict__ h)           // [Rp][H] bf16
{
    __shared__ unsigned short A[2][128 * BK];   // 32 KB
    __shared__ unsigned short B1[2][128 * BK];  // 32 KB
    __shared__ unsigned short B3[2][128 * BK];  // 32 KB

    const int b = blockIdx.x;
    const int bs = (b & 7) * (G1X / 8) + (b >> 3);
    int e = 0, mt = 0, nt = 0, found = 0, at = 0;
#pragma unroll
    for (int ee = 0; ee < N_EXP; ++ee) {
        int me = (offs[ee + 1] - offs[ee]) >> 7;
        int te = me * 16;
        if (!found && bs < at + te) {
            int loc = bs - at;
            nt = loc / me;
            mt = loc - nt * me;
            e = ee; found = 1;
        }
        at += te;
    }
    if (!found) return;
    const int m0 = offs[e] + mt * 128;
    const int n0 = nt * 128;                  // h-col base

    const int tid = threadIdx.x;
    const int lane = tid & 63, wid = tid >> 6;
    const int wm = wid >> 2, wn = wid & 3;    // 2M x 4N: wave tile 64m x 32n

    // A staging: 2 gload_lds / thread (pre-swizzled source, linear LDS)
    const unsigned short* asrc[2];
    unsigned aoff[2];
#pragma unroll
    for (int q = 0; q < 2; ++q) {
        int c = q * 512 + tid;
        int m = c >> 3, kc = c & 7;
        int kcs = kc ^ (m & 7);
        int tok = row_token[m0 + m];
        asrc[q] = xb + (size_t)tok * D_MODEL + kcs * 8;
        aoff[q] = (unsigned)c * 8u;
    }

    // B staging: direct f32 row-pairs from w1/w3. [64k][128n] tile each.
    // thread: p in {0,1}: kp = p*16 + (tid>>5), n4 = tid&31
    const int kpb = tid >> 5;                 // 0..15
    const int n4b = tid & 31;
    const float* w1e = w1 + (size_t)e * D_MODEL * HIDDEN + n0 + n4b * 4;
    const float* w3e = w3 + (size_t)e * D_MODEL * HIDDEN + n0 + n4b * 4;

    f32x4 r1lo[2], r1hi[2], r3lo[2], r3hi[2];

    f32x4 acc1[4][2], acc3[4][2];
    const f32x4 zf = {0.f, 0.f, 0.f, 0.f};
#pragma unroll
    for (int mi = 0; mi < 4; ++mi)
#pragma unroll
        for (int ni = 0; ni < 2; ++ni) { acc1[mi][ni] = zf; acc3[mi][ni] = zf; }

    // prologue: issue tile-0 loads
#pragma unroll
    for (int p = 0; p < 2; ++p) {
        size_t rb = (size_t)(2 * (p * 16 + kpb)) * HIDDEN;
        r1lo[p] = *(const f32x4*)(w1e + rb);
        r1hi[p] = *(const f32x4*)(w1e + rb + HIDDEN);
        r3lo[p] = *(const f32x4*)(w3e + rb);
        r3hi[p] = *(const f32x4*)(w3e + rb + HIDDEN);
    }
    gload_lds16(asrc[0], &A[0][aoff[0]]);
    gload_lds16(asrc[1], &A[0][aoff[1]]);

    int cur = 0;
#pragma unroll 1
    for (int kt = 0; kt < NT1; ++kt) {
        asm volatile("s_waitcnt vmcnt(0)" ::: "memory");
        // cvt + ds_write B(kt) -> LDS[cur]
        unsigned* B1u = (unsigned*)&B1[cur][0];
        unsigned* B3u = (unsigned*)&B3[cur][0];
#pragma unroll
        for (int p = 0; p < 2; ++p) {
            int kp = p * 16 + kpb;
#pragma unroll
            for (int j = 0; j < 4; ++j) {
                int n = n4b * 4 + j;
                unsigned col = (unsigned)kp ^ ((((unsigned)n >> 1) & 7u) << 2);
                B1u[n * 32 + col] = cvtpk(r1lo[p][j], r1hi[p][j]);
                B3u[n * 32 + col] = cvtpk(r3lo[p][j], r3hi[p][j]);
            }
        }
        asm volatile("s_waitcnt lgkmcnt(0)" ::: "memory");
        __builtin_amdgcn_s_barrier();

        // issue next tile loads
        if (kt + 1 < NT1) {
            const size_t kgo = (size_t)((kt + 1) * BK) * HIDDEN;
#pragma unroll
            for (int p = 0; p < 2; ++p) {
                size_t rb = kgo + (size_t)(2 * (p * 16 + kpb)) * HIDDEN;
                r1lo[p] = *(const f32x4*)(w1e + rb);
                r1hi[p] = *(const f32x4*)(w1e + rb + HIDDEN);
                r3lo[p] = *(const f32x4*)(w3e + rb);
                r3hi[p] = *(const f32x4*)(w3e + rb + HIDDEN);
            }
            const int ko = (kt + 1) * BK;
            gload_lds16(asrc[0] + ko, &A[cur ^ 1][aoff[0]]);
            gload_lds16(asrc[1] + ko, &A[cur ^ 1][aoff[1]]);
        }
        __builtin_amdgcn_sched_barrier(0);

        // MFMA on LDS[cur]
        const unsigned short* Ac = &A[cur][0];
        const unsigned short* B1c = &B1[cur][0];
        const unsigned short* B3c = &B3[cur][0];
#pragma unroll
        for (int kf = 0; kf < 2; ++kf) {
            bf16x8 a[4], b1f[2], b3f[2];
            int ke = kf * 32 + (lane >> 4) * 8;
#pragma unroll
            for (int mi = 0; mi < 4; ++mi) {
                int m = wm * 64 + mi * 16 + (lane & 15);
                a[mi] = *(const bf16x8*)(&Ac[m * BK + (ke ^ ((m & 7) * 8))]);
            }
#pragma unroll
            for (int ni = 0; ni < 2; ++ni) {
                int n = wn * 32 + ni * 16 + (lane & 15);
                int eo = n * BK + (ke ^ ((((unsigned)n >> 1) & 7u) << 3));
                b1f[ni] = *(const bf16x8*)(&B1c[eo]);
                b3f[ni] = *(const bf16x8*)(&B3c[eo]);
            }
            __builtin_amdgcn_s_setprio(1);
#pragma unroll
            for (int mi = 0; mi < 4; ++mi)
#pragma unroll
                for (int ni = 0; ni < 2; ++ni) {
                    acc1[mi][ni] = __builtin_amdgcn_mfma_f32_16x16x32_bf16(a[mi], b1f[ni], acc1[mi][ni], 0, 0, 0);
                    acc3[mi][ni] = __builtin_amdgcn_mfma_f32_16x16x32_bf16(a[mi], b3f[ni], acc3[mi][ni], 0, 0, 0);
                }
            __builtin_amdgcn_s_setprio(0);
        }
        cur ^= 1;
    }

    // epilogue: h = silu(acc1) * acc3 * w
#pragma unroll
    for (int mi = 0; mi < 4; ++mi) {
#pragma unroll
        for (int r = 0; r < 4; ++r) {
            int m = wm * 64 + mi * 16 + (lane >> 4) * 4 + r;
            float wgt = row_weight[m0 + m];
            size_t rowbase = (size_t)(m0 + m) * HIDDEN + n0;
#pragma unroll
            for (int ni = 0; ni < 2; ++ni) {
                float v1 = acc1[mi][ni][r], v3 = acc3[mi][ni][r];
                float sv = v1 / (1.f + __expf(-v1));
                int n = wn * 32 + ni * 16 + (lane & 15);
                h[rowbase + n] = f2bf(sv * v3 * wgt);
            }
        }
    }
}

// ---------------- GEMM2: direct-f32 B staging, 128m x 256n ----------------
__global__ __launch_bounds__(512, 1) void k_gemm2(
    const unsigned short* __restrict__ hh,   // [Rp][H] bf16
    const float* __restrict__ w2,            // [E][H][D] f32
    const int* __restrict__ offs,
    unsigned short* __restrict__ y)          // [Rp][D] bf16
{
    __shared__ unsigned short A[2][128 * BK];   // 32 KB
    __shared__ unsigned short B[2][256 * BK];   // 64 KB

    const int b = blockIdx.x;
    const int bs = (b & 7) * (G2X / 8) + (b >> 3);
    int e = 0, mt = 0, nt = 0, found = 0, at = 0;
#pragma unroll
    for (int ee = 0; ee < N_EXP; ++ee) {
        int me = (offs[ee + 1] - offs[ee]) >> 7;
        int te = me * 4;
        if (!found && bs < at + te) {
            int loc = bs - at;
            nt = loc / me;
            mt = loc - nt * me;
            e = ee; found = 1;
        }
        at += te;
    }
    if (!found) return;
    const int m0 = offs[e] + mt * 128;
    const int n0 = nt * 256;

    const int tid = threadIdx.x;
    const int lane = tid & 63, wid = tid >> 6;
    const int wm = wid >> 2, wn = wid & 3;    // wave tile 64m x 64n

    const unsigned short* asrc[2];
    unsigned aoff[2];
#pragma unroll
    for (int q = 0; q < 2; ++q) {
        int c = q * 512 + tid;
        int m = c >> 3, kc = c & 7;
        int kcs = kc ^ (m & 7);
        asrc[q] = hh + (size_t)(m0 + m) * HIDDEN + kcs * 8;
        aoff[q] = (unsigned)c * 8u;
    }

    // B staging: p in 0..3: kp = p*8 + wid (0..31), n4 = lane (0..63)
    const float* w2e = w2 + (size_t)e * HIDDEN * D_MODEL + n0 + lane * 4;

    f32x4 rlo[4], rhi[4];

    f32x4 acc[4][4];
    const f32x4 zf = {0.f, 0.f, 0.f, 0.f};
#pragma unroll
    for (int mi = 0; mi < 4; ++mi)
#pragma unroll
        for (int ni = 0; ni < 4; ++ni) acc[mi][ni] = zf;

#pragma unroll
    for (int p = 0; p < 4; ++p) {
        size_t rb = (size_t)(2 * (p * 8 + wid)) * D_MODEL;
        rlo[p] = *(const f32x4*)(w2e + rb);
        rhi[p] = *(const f32x4*)(w2e + rb + D_MODEL);
    }
    gload_lds16(asrc[0], &A[0][aoff[0]]);
    gload_lds16(asrc[1], &A[0][aoff[1]]);

    int cur = 0;
#pragma unroll 1
    for (int kt = 0; kt < NT2; ++kt) {
        asm volatile("s_waitcnt vmcnt(0)" ::: "memory");
        unsigned* Bu = (unsigned*)&B[cur][0];
#pragma unroll
        for (int p = 0; p < 4; ++p) {
            int kp = p * 8 + wid;
#pragma unroll
            for (int j = 0; j < 4; ++j) {
                int n = lane * 4 + j;
                unsigned col = (unsigned)kp ^ ((((unsigned)n >> 1) & 7u) << 2);
                Bu[n * 32 + col] = cvtpk(rlo[p][j], rhi[p][j]);
            }
        }
        asm volatile("s_waitcnt lgkmcnt(0)" ::: "memory");
        __builtin_amdgcn_s_barrier();

        if (kt + 1 < NT2) {
            const size_t kgo = (size_t)((kt + 1) * BK) * D_MODEL;
#pragma unroll
            for (int p = 0; p < 4; ++p) {
                size_t rb = kgo + (size_t)(2 * (p * 8 + wid)) * D_MODEL;
                rlo[p] = *(const f32x4*)(w2e + rb);
                rhi[p] = *(const f32x4*)(w2e + rb + D_MODEL);
            }
            const int ko = (kt + 1) * BK;
            gload_lds16(asrc[0] + ko, &A[cur ^ 1][aoff[0]]);
            gload_lds16(asrc[1] + ko, &A[cur ^ 1][aoff[1]]);
        }
        __builtin_amdgcn_sched_barrier(0);

        const unsigned short* Ac = &A[cur][0];
        const unsigned short* Bc = &B[cur][0];
#pragma unroll
        for (int kf = 0; kf < 2; ++kf) {
            bf16x8 a[4], bf[4];
            int ke = kf * 32 + (lane >> 4) * 8;
#pragma unroll
            for (int mi = 0; mi < 4; ++mi) {
                int m = wm * 64 + mi * 16 + (lane & 15);
                a[mi] = *(const bf16x8*)(&Ac[m * BK + (ke ^ ((m & 7) * 8))]);
            }
#pragma unroll
            for (int ni = 0; ni < 4; ++ni) {
                int n = wn * 64 + ni * 16 + (lane & 15);
                int eo = n * BK + (ke ^ ((((unsigned)n >> 1) & 7u) << 3));
                bf[ni] = *(const bf16x8*)(&Bc[eo]);
            }
            __builtin_amdgcn_s_setprio(1);
#pragma unroll
            for (int mi = 0; mi < 4; ++mi)
#pragma unroll
                for (int ni = 0; ni < 4; ++ni)
                    acc[mi][ni] = __builtin_amdgcn_mfma_f32_16x16x32_bf16(a[mi], bf[ni], acc[mi][ni], 0, 0, 0);
            __builtin_amdgcn_s_setprio(0);
        }
        cur ^= 1;
    }

#pragma unroll
    for (int mi = 0; mi < 4; ++mi) {
#pragma unroll
        for (int r = 0; r < 4; ++r) {
            int m = wm * 64 + mi * 16 + (lane >> 4) * 4 + r;
            size_t rowbase = (size_t)(m0 + m) * D_MODEL + n0;
#pragma unroll
            for (int ni = 0; ni < 4; ++ni) {
                int n = wn * 64 + ni * 16 + (lane & 15);
                y[rowbase + n] = f2bf(acc[mi][ni][r]);
            }
        }
    }
}

// ---------------- combine: out[t] = y[pos0] + y[pos1] ----------------
__global__ void k_combine(const unsigned short* __restrict__ y,
                          const int* __restrict__ tok_pos,
                          float* __restrict__ out, int n8) {
    int i = blockIdx.x * blockDim.x + threadIdx.x;
    if (i >= n8) return;
    int t = i >> 7;
    int c = (i & 127) * 8;
    int p0 = tok_pos[2 * t];
    int p1 = tok_pos[2 * t + 1];
    bf16x8 v0 = *(const bf16x8*)(y + (size_t)p0 * D_MODEL + c);
    bf16x8 v1 = *(const bf16x8*)(y + (size_t)p1 * D_MODEL + c);
    float* op = out + (size_t)t * D_MODEL + c;
    float4 o0, o1;
    o0.x = bf2f((unsigned short)v0[0]) + bf2f((unsigned short)v1[0]);
    o0.y = bf2f((unsigned short)v0[1]) + bf2f((unsigned short)v1[1]);
    o0.z = bf2f((unsigned short)v0[2]) + bf2f((unsigned short)v1[2]);
    o0.w = bf2f((unsigned short)v0[3]) + bf2f((unsigned short)v1[3]);
    o1.x = bf2f((unsigned short)v0[4]) + bf2f((unsigned short)v1[4]);
    o1.y = bf2f((unsigned short)v0[5]) + bf2f((unsigned short)v1[5]);
    o1.z = bf2f((unsigned short)v0[6]) + bf2f((unsigned short)v1[6]);
    o1.w = bf2f((unsigned short)v0[7]) + bf2f((unsigned short)v1[7]);
    *(float4*)op = o0;
    *(float4*)(op + 4) = o1;
}

extern "C" void kernel_launch(void* const* d_in, const int* in_sizes, int n_in,
                              void* d_out, int out_size, void* d_ws, size_t ws_size,
                              hipStream_t stream) {
    const float* x  = (const float*)d_in[0];
    const float* wr = (const float*)d_in[1];
    const float* w1 = (const float*)d_in[2];
    const float* w3 = (const float*)d_in[3];
    const float* w2 = (const float*)d_in[4];
    float* out = (float*)d_out;

    const int T = in_sizes[0] / D_MODEL;    // 4096
    const int Rp = T * TOPK + N_EXP * PADM; // 9216

    char* ws = (char*)d_ws;
    size_t o = 0;
    unsigned short* xb = (unsigned short*)(ws + o); o += (size_t)T * D_MODEL * 2;
    unsigned short* h  = (unsigned short*)(ws + o); o += (size_t)Rp * HIDDEN * 2;
    unsigned short* y  = (unsigned short*)(ws + o); o += (size_t)Rp * D_MODEL * 2;
    int*   row_token  = (int*)(ws + o);   o += (size_t)Rp * 4;
    float* row_weight = (float*)(ws + o); o += (size_t)Rp * 4;
    int*   tok_e      = (int*)(ws + o);   o += (size_t)2 * T * 4;
    float* tok_w      = (float*)(ws + o); o += (size_t)2 * T * 4;
    int*   tok_pos    = (int*)(ws + o);   o += (size_t)2 * T * 4;
    int*   counts     = (int*)(ws + o);   o += 16 * 4;
    int*   offs       = (int*)(ws + o);   o += 16 * 4;

    hipMemsetAsync(counts, 0, 16 * 4, stream);
    hipMemsetAsync(row_token, 0, (size_t)Rp * 4, stream);
    hipMemsetAsync(row_weight, 0, (size_t)Rp * 4, stream);

    k_pre<<<(T + 3) / 4, 256, 0, stream>>>(x, wr, xb, tok_e, tok_w, counts, T);

    k_scan_scatter<<<1, 1024, 0, stream>>>(counts, tok_e, tok_w, offs,
                                           row_token, row_weight, tok_pos, T);

    k_gemm1<<<G1X, 512, 0, stream>>>(xb, w1, w3, row_token, row_weight, offs, h);
    k_gemm2<<<G2X, 512, 0, stream>>>(h, w2, offs, y);

    int n8 = T * D_MODEL / 8;
    k_combine<<<(n8 + 255) / 256, 256, 0, stream>>>(y, tok_pos, out, n8);
}

// Round 15
// 367.545 us; speedup vs baseline: 1.4142x; 1.4142x over previous
//
#include <hip/hip_runtime.h>
#include <stdint.h>

#define D_MODEL 1024
#define N_EXP   8
#define HIDDEN  2048
#define TOPK    2

#define BK    64
#define PADM  128
#define NT1   (D_MODEL / BK)   // 16
#define NT2   (HIDDEN / BK)    // 32
#define G1X   1152             // 72 m-tiles(128) x 16 n-tiles(256 of 2H)
#define G2X   288              // 72 m-tiles(128) x 4 n-tiles(256 of D)

typedef short bf16x8 __attribute__((ext_vector_type(8)));
typedef float f32x4 __attribute__((ext_vector_type(4)));
typedef unsigned u32x4 __attribute__((ext_vector_type(4)));

__device__ __forceinline__ unsigned short f2bf(float f) {
    union { float f; unsigned u; } v; v.f = f;
    unsigned r = v.u + 0x7fffu + ((v.u >> 16) & 1u);
    return (unsigned short)(r >> 16);
}

__device__ __forceinline__ float bf2f(unsigned short u) {
    union { unsigned u; float f; } v; v.u = (unsigned)u << 16; return v.f;
}

// pack two f32 -> u32 of 2 bf16 (RNE); low16 = src0
__device__ __forceinline__ unsigned cvtpk(float a, float b) {
    unsigned r;
    asm("v_cvt_pk_bf16_f32 %0, %1, %2" : "=v"(r) : "v"(a), "v"(b));
    return r;
}

__device__ __forceinline__ void gload_lds16(const void* g, void* l) {
    __builtin_amdgcn_global_load_lds(
        (const __attribute__((address_space(1))) void*)g,
        (__attribute__((address_space(3))) void*)l, 16, 0, 0);
}

// ---------------- router + x->bf16 convert ----------------
__global__ __launch_bounds__(256) void k_pre(
    const float* __restrict__ x, const float* __restrict__ wr,
    unsigned short* __restrict__ xb,
    int* __restrict__ tok_e, float* __restrict__ tok_w,
    int* __restrict__ counts, int T)
{
    int t = blockIdx.x * 4 + (threadIdx.x >> 6);
    int lane = threadIdx.x & 63;
    if (t >= T) return;
    const float4* xr = (const float4*)(x + (size_t)t * D_MODEL);
    float acc[N_EXP];
#pragma unroll
    for (int e = 0; e < N_EXP; ++e) acc[e] = 0.f;
#pragma unroll
    for (int j = 0; j < 4; ++j) {
        int c = j * 64 + lane;
        float4 v = xr[c];
        ushort4 pk;
        pk.x = f2bf(v.x); pk.y = f2bf(v.y); pk.z = f2bf(v.z); pk.w = f2bf(v.w);
        *(ushort4*)(xb + (size_t)t * D_MODEL + c * 4) = pk;
        const float4* w4 = (const float4*)(wr + (size_t)c * 4 * N_EXP);
#pragma unroll
        for (int k = 0; k < 4; ++k) {
            float xv = (k == 0) ? v.x : (k == 1) ? v.y : (k == 2) ? v.z : v.w;
            float4 wa = w4[k * 2], wb = w4[k * 2 + 1];
            acc[0] += xv * wa.x; acc[1] += xv * wa.y; acc[2] += xv * wa.z; acc[3] += xv * wa.w;
            acc[4] += xv * wb.x; acc[5] += xv * wb.y; acc[6] += xv * wb.z; acc[7] += xv * wb.w;
        }
    }
#pragma unroll
    for (int off = 32; off > 0; off >>= 1) {
#pragma unroll
        for (int e = 0; e < N_EXP; ++e) acc[e] += __shfl_down(acc[e], off, 64);
    }
    if (lane == 0) {
        float mx = acc[0];
#pragma unroll
        for (int e = 1; e < N_EXP; ++e) mx = fmaxf(mx, acc[e]);
        float p[N_EXP], den = 0.f;
#pragma unroll
        for (int e = 0; e < N_EXP; ++e) { p[e] = __expf(acc[e] - mx); den += p[e]; }
        float inv = 1.f / den;
        int e0 = 0; float v0 = acc[0];
#pragma unroll
        for (int e = 1; e < N_EXP; ++e) if (acc[e] > v0) { v0 = acc[e]; e0 = e; }
        int e1 = -1; float v1 = -1e30f;
#pragma unroll
        for (int e = 0; e < N_EXP; ++e) if (e != e0 && acc[e] > v1) { v1 = acc[e]; e1 = e; }
        tok_e[2 * t] = e0;     tok_w[2 * t] = p[e0] * inv;
        tok_e[2 * t + 1] = e1; tok_w[2 * t + 1] = p[e1] * inv;
        atomicAdd(&counts[e0], 1);
        atomicAdd(&counts[e1], 1);
    }
}

// ---------------- weight transpose: full-row-burst reads ----------------
// Block owns a 64-row slab, sweeps all cols in 256-col strips.
// Phase 1: each instr = one contiguous 1KB row segment (64 lanes x 16B).
// blocks 0..255: w1/w3 -> w13t interleaved; 256..511: w2 -> w2t.
__global__ __launch_bounds__(256) void k_wt(
    const float* __restrict__ w1, const float* __restrict__ w3, const float* __restrict__ w2,
    unsigned short* __restrict__ w13t, unsigned short* __restrict__ w2t)
{
    __shared__ unsigned tile[256][32];    // 32 KB: [c][rr ^ sw(c)]
    const int bx = blockIdx.x;
    const int tid = threadIdx.x;
    const int w = tid >> 6, lane = tid & 63;

    const float* in; int Cc, nstr, r0, e, moff; bool is13;
    if (bx < 256) {
        int z = bx >> 4;                  // 0..15
        int mat = z >> 3; e = z & 7;
        in = (mat ? w3 : w1) + (size_t)e * D_MODEL * HIDDEN;
        Cc = HIDDEN; nstr = 8;
        r0 = (bx & 15) * 64;
        is13 = true; moff = mat ? 16 : 0;
    } else {
        int b2 = bx - 256;
        e = b2 >> 5;
        in = w2 + (size_t)e * HIDDEN * D_MODEL;
        Cc = D_MODEL; nstr = 4;
        r0 = (b2 & 31) * 64;
        is13 = false; moff = 0;
    }

    for (int s = 0; s < nstr; ++s) {
        const int cs = s * 256;
        // phase 1: 16 x 1KB contiguous row-segment reads per wave
        f32x4 v[16];
#pragma unroll
        for (int i = 0; i < 16; ++i) {
            int r = w * 16 + i;
            v[i] = *(const f32x4*)(in + (size_t)(r0 + r) * Cc + cs + lane * 4);
        }
        if (s) __syncthreads();           // prior strip's writes done before overwrite
        // phase 2: cvt + pack own r-pairs, XOR-swizzled LDS stores
#pragma unroll
        for (int j = 0; j < 4; ++j) {
            int c = lane * 4 + j;
            unsigned sw = (((unsigned)c >> 2) & 7u) << 2;
#pragma unroll
            for (int p = 0; p < 8; ++p) {
                tile[c][(unsigned)(w * 8 + p) ^ sw] = cvtpk(v[2 * p][j], v[2 * p + 1][j]);
            }
        }
        __syncthreads();
        // phase 3: 256 threads write 256 out-rows x 128B
        {
            int c = tid;
            int C = cs + c;
            unsigned sw = (((unsigned)c >> 2) & 7u) << 2;
            unsigned short* outp;
            if (is13) {
                int r13 = ((C >> 4) << 5) + moff + (C & 15);
                outp = w13t + ((size_t)e * (2 * HIDDEN) + r13) * D_MODEL + r0;
            } else {
                outp = w2t + ((size_t)e * D_MODEL + C) * HIDDEN + r0;
            }
#pragma unroll
            for (int k = 0; k < 8; ++k) {
                u32x4 d = *(const u32x4*)(&tile[c][(unsigned)(k * 4) ^ sw]);
                *(u32x4*)(outp + k * 8) = d;
            }
        }
    }
}

// ---------------- scan (padded to PADM) + scatter, single block ----------------
__global__ void k_scan_scatter(const int* __restrict__ counts,
                               const int* __restrict__ tok_e, const float* __restrict__ tok_w,
                               int* __restrict__ offs,
                               int* __restrict__ row_token, float* __restrict__ row_weight,
                               int* __restrict__ tok_pos, int T) {
    __shared__ int scurs[N_EXP];
    if (threadIdx.x == 0) {
        int s = 0;
        for (int e = 0; e < N_EXP; ++e) {
            offs[e] = s; scurs[e] = s;
            s += ((counts[e] + PADM - 1) / PADM) * PADM;
        }
        offs[N_EXP] = s;
    }
    __syncthreads();
    for (int i = threadIdx.x; i < 2 * T; i += blockDim.x) {
        int e = tok_e[i];
        int pos = atomicAdd(&scurs[e], 1);
        row_token[pos] = i >> 1;
        row_weight[pos] = tok_w[i];
        tok_pos[i] = pos;
    }
}

// ---------------- GEMM1: 128x256, 3-buf distance-2 counted-vmcnt pipeline ----------------
__global__ __launch_bounds__(512, 1) void k_gemm1(
    const unsigned short* __restrict__ xb,    // [T][D] bf16
    const unsigned short* __restrict__ w13t,  // [E][2H][D] bf16 interleaved
    const int* __restrict__ row_token,
    const float* __restrict__ row_weight,
    const int* __restrict__ offs,             // [E+1] 128-padded
    unsigned short* __restrict__ h)           // [Rp][H] bf16
{
    __shared__ unsigned short A[3][128 * BK];   // 3 x 16 KB
    __shared__ unsigned short B[3][256 * BK];   // 3 x 32 KB

    const int b = blockIdx.x;
    const int bs = (b & 7) * (G1X / 8) + (b >> 3);
    int e = 0, mt = 0, nt = 0, found = 0, at = 0;
#pragma unroll
    for (int ee = 0; ee < N_EXP; ++ee) {
        int me = (offs[ee + 1] - offs[ee]) >> 7;
        int te = me * 16;
        if (!found && bs < at + te) {
            int loc = bs - at;
            nt = loc / me;
            mt = loc - nt * me;
            e = ee; found = 1;
        }
        at += te;
    }
    if (!found) return;
    const int m0 = offs[e] + mt * 128;
    const int n0b = nt * 256;

    const int tid = threadIdx.x;
    const int lane = tid & 63, wid = tid >> 6;
    const int wm = wid >> 2, wn = wid & 3;     // 2M x 4N, wave tile 64x64

    const unsigned short* asrc[2];
    unsigned aoff[2];
#pragma unroll
    for (int q = 0; q < 2; ++q) {
        int c = q * 512 + tid;
        int m = c >> 3, kc = c & 7;
        int kcs = kc ^ (m & 7);
        int tok = row_token[m0 + m];
        asrc[q] = xb + (size_t)tok * D_MODEL + kcs * 8;
        aoff[q] = (unsigned)c * 8u;
    }
    const unsigned short* bsrc[4];
    unsigned boff[4];
#pragma unroll
    for (int q = 0; q < 4; ++q) {
        int c = q * 512 + tid;
        int n = c >> 3, kc = c & 7;
        int kcs = kc ^ (n & 7);
        bsrc[q] = w13t + ((size_t)e * (2 * HIDDEN) + n0b + n) * D_MODEL + kcs * 8;
        boff[q] = (unsigned)c * 8u;
    }

    f32x4 acc[4][4];
    const f32x4 zf = {0.f, 0.f, 0.f, 0.f};
#pragma unroll
    for (int mi = 0; mi < 4; ++mi)
#pragma unroll
        for (int ni = 0; ni < 4; ++ni) acc[mi][ni] = zf;

#pragma unroll
    for (int t = 0; t < 2; ++t) {
        const int ko = t * BK;
        gload_lds16(asrc[0] + ko, &A[t][aoff[0]]);
        gload_lds16(asrc[1] + ko, &A[t][aoff[1]]);
        gload_lds16(bsrc[0] + ko, &B[t][boff[0]]);
        gload_lds16(bsrc[1] + ko, &B[t][boff[1]]);
        gload_lds16(bsrc[2] + ko, &B[t][boff[2]]);
        gload_lds16(bsrc[3] + ko, &B[t][boff[3]]);
    }

    int cur = 0;
#pragma unroll 1
    for (int kt = 0; kt < NT1; ++kt) {
        if (kt == NT1 - 1) asm volatile("s_waitcnt vmcnt(0)" ::: "memory");
        else               asm volatile("s_waitcnt vmcnt(6)" ::: "memory");
        __builtin_amdgcn_s_barrier();

        unsigned short* Ac = &A[cur][0];
        unsigned short* Bc = &B[cur][0];
        const int nb = (cur + 2 >= 3) ? (cur - 1) : (cur + 2);
        const int ko = (kt + 2) * BK;
        const bool pf = (kt + 2 < NT1);

        // phase 0: kf = 0
        {
            bf16x8 a0[4], b0[4];
            int ke = (lane >> 4) * 8;
#pragma unroll
            for (int mi = 0; mi < 4; ++mi) {
                int m = wm * 64 + mi * 16 + (lane & 15);
                a0[mi] = *(const bf16x8*)(&Ac[m * BK + (ke ^ ((m & 7) * 8))]);
            }
#pragma unroll
            for (int ni = 0; ni < 4; ++ni) {
                int n = wn * 64 + ni * 16 + (lane & 15);
                b0[ni] = *(const bf16x8*)(&Bc[n * BK + (ke ^ ((n & 7) * 8))]);
            }
            if (pf) {
                gload_lds16(asrc[0] + ko, &A[nb][aoff[0]]);
                gload_lds16(asrc[1] + ko, &A[nb][aoff[1]]);
                gload_lds16(bsrc[0] + ko, &B[nb][boff[0]]);
            }
            __builtin_amdgcn_s_barrier();
            __builtin_amdgcn_s_setprio(1);
#pragma unroll
            for (int mi = 0; mi < 4; ++mi)
#pragma unroll
                for (int ni = 0; ni < 4; ++ni)
                    acc[mi][ni] = __builtin_amdgcn_mfma_f32_16x16x32_bf16(a0[mi], b0[ni], acc[mi][ni], 0, 0, 0);
            __builtin_amdgcn_s_setprio(0);
        }
        // phase 1: kf = 1
        {
            bf16x8 a1[4], b1[4];
            int ke = 32 + (lane >> 4) * 8;
#pragma unroll
            for (int mi = 0; mi < 4; ++mi) {
                int m = wm * 64 + mi * 16 + (lane & 15);
                a1[mi] = *(const bf16x8*)(&Ac[m * BK + (ke ^ ((m & 7) * 8))]);
            }
#pragma unroll
            for (int ni = 0; ni < 4; ++ni) {
                int n = wn * 64 + ni * 16 + (lane & 15);
                b1[ni] = *(const bf16x8*)(&Bc[n * BK + (ke ^ ((n & 7) * 8))]);
            }
            if (pf) {
                gload_lds16(bsrc[1] + ko, &B[nb][boff[1]]);
                gload_lds16(bsrc[2] + ko, &B[nb][boff[2]]);
                gload_lds16(bsrc[3] + ko, &B[nb][boff[3]]);
            }
            __builtin_amdgcn_s_barrier();
            __builtin_amdgcn_s_setprio(1);
#pragma unroll
            for (int mi = 0; mi < 4; ++mi)
#pragma unroll
                for (int ni = 0; ni < 4; ++ni)
                    acc[mi][ni] = __builtin_amdgcn_mfma_f32_16x16x32_bf16(a1[mi], b1[ni], acc[mi][ni], 0, 0, 0);
            __builtin_amdgcn_s_setprio(0);
        }
        cur = (cur == 2) ? 0 : (cur + 1);
    }

    // epilogue: silu(acc[.][even]) * acc[.][odd] -> h
    const int g0 = (n0b + wn * 64) >> 5;
#pragma unroll
    for (int mi = 0; mi < 4; ++mi) {
#pragma unroll
        for (int r = 0; r < 4; ++r) {
            int m = wm * 64 + mi * 16 + (lane >> 4) * 4 + r;
            float wgt = row_weight[m0 + m];
            size_t rowbase = (size_t)(m0 + m) * HIDDEN;
#pragma unroll
            for (int p = 0; p < 2; ++p) {
                float v1 = acc[mi][2 * p][r], v3 = acc[mi][2 * p + 1][r];
                float sv = v1 / (1.f + __expf(-v1));
                int hc = (g0 + p) * 16 + (lane & 15);
                h[rowbase + hc] = f2bf(sv * v3 * wgt);
            }
        }
    }
}

// ---------------- GEMM2: 128x256, 3-buf distance-2 counted-vmcnt pipeline ----------------
__global__ __launch_bounds__(512, 1) void k_gemm2(
    const unsigned short* __restrict__ h,    // [Rp][H] bf16
    const unsigned short* __restrict__ w2t,  // [E][D][H] bf16
    const int* __restrict__ offs,
    unsigned short* __restrict__ y)          // [Rp][D] bf16
{
    __shared__ unsigned short A[3][128 * BK];   // 3 x 16 KB
    __shared__ unsigned short B[3][256 * BK];   // 3 x 32 KB

    const int b = blockIdx.x;
    const int bs = (b & 7) * (G2X / 8) + (b >> 3);
    int e = 0, mt = 0, nt = 0, found = 0, at = 0;
#pragma unroll
    for (int ee = 0; ee < N_EXP; ++ee) {
        int me = (offs[ee + 1] - offs[ee]) >> 7;
        int te = me * 4;
        if (!found && bs < at + te) {
            int loc = bs - at;
            nt = loc / me;
            mt = loc - nt * me;
            e = ee; found = 1;
        }
        at += te;
    }
    if (!found) return;
    const int m0 = offs[e] + mt * 128;
    const int n0 = nt * 256;

    const int tid = threadIdx.x;
    const int lane = tid & 63, wid = tid >> 6;
    const int wm = wid >> 2, wn = wid & 3;

    const unsigned short* asrc[2];
    unsigned aoff[2];
#pragma unroll
    for (int q = 0; q < 2; ++q) {
        int c = q * 512 + tid;
        int m = c >> 3, kc = c & 7;
        int kcs = kc ^ (m & 7);
        asrc[q] = h + (size_t)(m0 + m) * HIDDEN + kcs * 8;
        aoff[q] = (unsigned)c * 8u;
    }
    const unsigned short* bsrc[4];
    unsigned boff[4];
#pragma unroll
    for (int q = 0; q < 4; ++q) {
        int c = q * 512 + tid;
        int n = c >> 3, kc = c & 7;
        int kcs = kc ^ (n & 7);
        bsrc[q] = w2t + ((size_t)e * D_MODEL + n0 + n) * HIDDEN + kcs * 8;
        boff[q] = (unsigned)c * 8u;
    }

    f32x4 acc[4][4];
    const f32x4 zf = {0.f, 0.f, 0.f, 0.f};
#pragma unroll
    for (int mi = 0; mi < 4; ++mi)
#pragma unroll
        for (int ni = 0; ni < 4; ++ni) acc[mi][ni] = zf;

#pragma unroll
    for (int t = 0; t < 2; ++t) {
        const int ko = t * BK;
        gload_lds16(asrc[0] + ko, &A[t][aoff[0]]);
        gload_lds16(asrc[1] + ko, &A[t][aoff[1]]);
        gload_lds16(bsrc[0] + ko, &B[t][boff[0]]);
        gload_lds16(bsrc[1] + ko, &B[t][boff[1]]);
        gload_lds16(bsrc[2] + ko, &B[t][boff[2]]);
        gload_lds16(bsrc[3] + ko, &B[t][boff[3]]);
    }

    int cur = 0;
#pragma unroll 1
    for (int kt = 0; kt < NT2; ++kt) {
        if (kt == NT2 - 1) asm volatile("s_waitcnt vmcnt(0)" ::: "memory");
        else               asm volatile("s_waitcnt vmcnt(6)" ::: "memory");
        __builtin_amdgcn_s_barrier();

        unsigned short* Ac = &A[cur][0];
        unsigned short* Bc = &B[cur][0];
        const int nb = (cur + 2 >= 3) ? (cur - 1) : (cur + 2);
        const int ko = (kt + 2) * BK;
        const bool pf = (kt + 2 < NT2);

        // phase 0: kf = 0
        {
            bf16x8 a0[4], b0[4];
            int ke = (lane >> 4) * 8;
#pragma unroll
            for (int mi = 0; mi < 4; ++mi) {
                int m = wm * 64 + mi * 16 + (lane & 15);
                a0[mi] = *(const bf16x8*)(&Ac[m * BK + (ke ^ ((m & 7) * 8))]);
            }
#pragma unroll
            for (int ni = 0; ni < 4; ++ni) {
                int n = wn * 64 + ni * 16 + (lane & 15);
                b0[ni] = *(const bf16x8*)(&Bc[n * BK + (ke ^ ((n & 7) * 8))]);
            }
            if (pf) {
                gload_lds16(asrc[0] + ko, &A[nb][aoff[0]]);
                gload_lds16(asrc[1] + ko, &A[nb][aoff[1]]);
                gload_lds16(bsrc[0] + ko, &B[nb][boff[0]]);
            }
            __builtin_amdgcn_s_barrier();
            __builtin_amdgcn_s_setprio(1);
#pragma unroll
            for (int mi = 0; mi < 4; ++mi)
#pragma unroll
                for (int ni = 0; ni < 4; ++ni)
                    acc[mi][ni] = __builtin_amdgcn_mfma_f32_16x16x32_bf16(a0[mi], b0[ni], acc[mi][ni], 0, 0, 0);
            __builtin_amdgcn_s_setprio(0);
        }
        // phase 1: kf = 1
        {
            bf16x8 a1[4], b1[4];
            int ke = 32 + (lane >> 4) * 8;
#pragma unroll
            for (int mi = 0; mi < 4; ++mi) {
                int m = wm * 64 + mi * 16 + (lane & 15);
                a1[mi] = *(const bf16x8*)(&Ac[m * BK + (ke ^ ((m & 7) * 8))]);
            }
#pragma unroll
            for (int ni = 0; ni < 4; ++ni) {
                int n = wn * 64 + ni * 16 + (lane & 15);
                b1[ni] = *(const bf16x8*)(&Bc[n * BK + (ke ^ ((n & 7) * 8))]);
            }
            if (pf) {
                gload_lds16(bsrc[1] + ko, &B[nb][boff[1]]);
                gload_lds16(bsrc[2] + ko, &B[nb][boff[2]]);
                gload_lds16(bsrc[3] + ko, &B[nb][boff[3]]);
            }
            __builtin_amdgcn_s_barrier();
            __builtin_amdgcn_s_setprio(1);
#pragma unroll
            for (int mi = 0; mi < 4; ++mi)
#pragma unroll
                for (int ni = 0; ni < 4; ++ni)
                    acc[mi][ni] = __builtin_amdgcn_mfma_f32_16x16x32_bf16(a1[mi], b1[ni], acc[mi][ni], 0, 0, 0);
            __builtin_amdgcn_s_setprio(0);
        }
        cur = (cur == 2) ? 0 : (cur + 1);
    }

#pragma unroll
    for (int mi = 0; mi < 4; ++mi) {
#pragma unroll
        for (int r = 0; r < 4; ++r) {
            int m = wm * 64 + mi * 16 + (lane >> 4) * 4 + r;
            size_t rowbase = (size_t)(m0 + m) * D_MODEL + n0;
#pragma unroll
            for (int ni = 0; ni < 4; ++ni) {
                int n = wn * 64 + ni * 16 + (lane & 15);
                y[rowbase + n] = f2bf(acc[mi][ni][r]);
            }
        }
    }
}

// ---------------- combine: out[t] = y[pos0] + y[pos1] ----------------
__global__ void k_combine(const unsigned short* __restrict__ y,
                          const int* __restrict__ tok_pos,
                          float* __restrict__ out, int n8) {
    int i = blockIdx.x * blockDim.x + threadIdx.x;
    if (i >= n8) return;
    int t = i >> 7;
    int c = (i & 127) * 8;
    int p0 = tok_pos[2 * t];
    int p1 = tok_pos[2 * t + 1];
    bf16x8 v0 = *(const bf16x8*)(y + (size_t)p0 * D_MODEL + c);
    bf16x8 v1 = *(const bf16x8*)(y + (size_t)p1 * D_MODEL + c);
    float* op = out + (size_t)t * D_MODEL + c;
    float4 o0, o1;
    o0.x = bf2f((unsigned short)v0[0]) + bf2f((unsigned short)v1[0]);
    o0.y = bf2f((unsigned short)v0[1]) + bf2f((unsigned short)v1[1]);
    o0.z = bf2f((unsigned short)v0[2]) + bf2f((unsigned short)v1[2]);
    o0.w = bf2f((unsigned short)v0[3]) + bf2f((unsigned short)v1[3]);
    o1.x = bf2f((unsigned short)v0[4]) + bf2f((unsigned short)v1[4]);
    o1.y = bf2f((unsigned short)v0[5]) + bf2f((unsigned short)v1[5]);
    o1.z = bf2f((unsigned short)v0[6]) + bf2f((unsigned short)v1[6]);
    o1.w = bf2f((unsigned short)v0[7]) + bf2f((unsigned short)v1[7]);
    *(float4*)op = o0;
    *(float4*)(op + 4) = o1;
}

extern "C" void kernel_launch(void* const* d_in, const int* in_sizes, int n_in,
                              void* d_out, int out_size, void* d_ws, size_t ws_size,
                              hipStream_t stream) {
    const float* x  = (const float*)d_in[0];
    const float* wr = (const float*)d_in[1];
    const float* w1 = (const float*)d_in[2];
    const float* w3 = (const float*)d_in[3];
    const float* w2 = (const float*)d_in[4];
    float* out = (float*)d_out;

    const int T = in_sizes[0] / D_MODEL;    // 4096
    const int Rp = T * TOPK + N_EXP * PADM; // 9216

    char* ws = (char*)d_ws;
    size_t o = 0;
    unsigned short* xb   = (unsigned short*)(ws + o); o += (size_t)T * D_MODEL * 2;
    unsigned short* h    = (unsigned short*)(ws + o); o += (size_t)Rp * HIDDEN * 2;
    unsigned short* w13t = (unsigned short*)(ws + o); o += (size_t)N_EXP * 2 * HIDDEN * D_MODEL * 2;
    unsigned short* w2t  = (unsigned short*)(ws + o); o += (size_t)N_EXP * D_MODEL * HIDDEN * 2;
    int*   row_token  = (int*)(ws + o);   o += (size_t)Rp * 4;
    float* row_weight = (float*)(ws + o); o += (size_t)Rp * 4;
    int*   tok_e      = (int*)(ws + o);   o += (size_t)2 * T * 4;
    float* tok_w      = (float*)(ws + o); o += (size_t)2 * T * 4;
    int*   tok_pos    = (int*)(ws + o);   o += (size_t)2 * T * 4;
    int*   counts     = (int*)(ws + o);   o += 16 * 4;
    int*   offs       = (int*)(ws + o);   o += 16 * 4;

    // y aliases w13t (dead after gemm1)
    unsigned short* y = w13t;

    hipMemsetAsync(counts, 0, 16 * 4, stream);
    hipMemsetAsync(row_token, 0, (size_t)Rp * 4, stream);
    hipMemsetAsync(row_weight, 0, (size_t)Rp * 4, stream);

    k_pre<<<(T + 3) / 4, 256, 0, stream>>>(x, wr, xb, tok_e, tok_w, counts, T);
    k_wt<<<512, 256, 0, stream>>>(w1, w3, w2, w13t, w2t);

    k_scan_scatter<<<1, 1024, 0, stream>>>(counts, tok_e, tok_w, offs,
                                           row_token, row_weight, tok_pos, T);

    k_gemm1<<<G1X, 512, 0, stream>>>(xb, w13t, row_token, row_weight, offs, h);
    k_gemm2<<<G2X, 512, 0, stream>>>(h, w2t, offs, y);

    int n8 = T * D_MODEL / 8;
    k_combine<<<(n8 + 255) / 256, 256, 0, stream>>>(y, tok_pos, out, n8);
}

// Round 16
// 307.845 us; speedup vs baseline: 1.6885x; 1.1939x over previous
//
#include <hip/hip_runtime.h>
#include <stdint.h>

#define D_MODEL 1024
#define N_EXP   8
#define HIDDEN  2048
#define TOPK    2

#define BK    32
#define PADM  128
#define NT1   (D_MODEL / BK)   // 32
#define NT2   (HIDDEN / BK)    // 64
#define G1X   1152             // 72 m-tiles(128) x 16 n-tiles(256 of 2H)
#define G2X   288              // 72 m-tiles(128) x 4 n-tiles(256 of D)

typedef short bf16x8 __attribute__((ext_vector_type(8)));
typedef float f32x4 __attribute__((ext_vector_type(4)));
typedef unsigned u32x4 __attribute__((ext_vector_type(4)));

__device__ __forceinline__ unsigned short f2bf(float f) {
    union { float f; unsigned u; } v; v.f = f;
    unsigned r = v.u + 0x7fffu + ((v.u >> 16) & 1u);
    return (unsigned short)(r >> 16);
}

__device__ __forceinline__ float bf2f(unsigned short u) {
    union { unsigned u; float f; } v; v.u = (unsigned)u << 16; return v.f;
}

__device__ __forceinline__ void gload_lds16(const void* g, void* l) {
    __builtin_amdgcn_global_load_lds(
        (const __attribute__((address_space(1))) void*)g,
        (__attribute__((address_space(3))) void*)l, 16, 0, 0);
}

// ---------------- fused prep (R11-exact): router + x->bf16 AND weight transpose ----------------
__global__ __launch_bounds__(256) void k_prep(
    const float* __restrict__ x, const float* __restrict__ wr,
    const float* __restrict__ w1, const float* __restrict__ w3, const float* __restrict__ w2,
    unsigned short* __restrict__ xb,
    unsigned short* __restrict__ w13t, unsigned short* __restrict__ w2t,
    int* __restrict__ tok_e, float* __restrict__ tok_w,
    int* __restrict__ counts, int T, int nrouter)
{
    __shared__ unsigned tls[128][32];     // 16 KB
    const int bx = blockIdx.x;
    const int tid = threadIdx.x;

    if (bx < nrouter) {
        int t = bx * 4 + (tid >> 6);
        int lane = tid & 63;
        if (t >= T) return;
        const float4* xr = (const float4*)(x + (size_t)t * D_MODEL);
        float acc[N_EXP];
#pragma unroll
        for (int e = 0; e < N_EXP; ++e) acc[e] = 0.f;
#pragma unroll
        for (int j = 0; j < 4; ++j) {
            int c = j * 64 + lane;
            float4 v = xr[c];
            ushort4 pk;
            pk.x = f2bf(v.x); pk.y = f2bf(v.y); pk.z = f2bf(v.z); pk.w = f2bf(v.w);
            *(ushort4*)(xb + (size_t)t * D_MODEL + c * 4) = pk;
            const float4* w4 = (const float4*)(wr + (size_t)c * 4 * N_EXP);
#pragma unroll
            for (int k = 0; k < 4; ++k) {
                float xv = (k == 0) ? v.x : (k == 1) ? v.y : (k == 2) ? v.z : v.w;
                float4 wa = w4[k * 2], wb = w4[k * 2 + 1];
                acc[0] += xv * wa.x; acc[1] += xv * wa.y; acc[2] += xv * wa.z; acc[3] += xv * wa.w;
                acc[4] += xv * wb.x; acc[5] += xv * wb.y; acc[6] += xv * wb.z; acc[7] += xv * wb.w;
            }
        }
#pragma unroll
        for (int off = 32; off > 0; off >>= 1) {
#pragma unroll
            for (int e = 0; e < N_EXP; ++e) acc[e] += __shfl_down(acc[e], off, 64);
        }
        if (lane == 0) {
            float mx = acc[0];
#pragma unroll
            for (int e = 1; e < N_EXP; ++e) mx = fmaxf(mx, acc[e]);
            float p[N_EXP], den = 0.f;
#pragma unroll
            for (int e = 0; e < N_EXP; ++e) { p[e] = __expf(acc[e] - mx); den += p[e]; }
            float inv = 1.f / den;
            int e0 = 0; float v0 = acc[0];
#pragma unroll
            for (int e = 1; e < N_EXP; ++e) if (acc[e] > v0) { v0 = acc[e]; e0 = e; }
            int e1 = -1; float v1 = -1e30f;
#pragma unroll
            for (int e = 0; e < N_EXP; ++e) if (e != e0 && acc[e] > v1) { v1 = acc[e]; e1 = e; }
            tok_e[2 * t] = e0;     tok_w[2 * t] = p[e0] * inv;
            tok_e[2 * t + 1] = e1; tok_w[2 * t + 1] = p[e1] * inv;
            atomicAdd(&counts[e0], 1);
            atomicAdd(&counts[e1], 1);
        }
        return;
    }

    // ---- weight convert + transpose, [64 r][128 c] tile ----
    const int b2 = bx - nrouter;          // 0..6143
    const int z = b2 >> 8;                // 0..23
    const int inner = b2 & 255;
    const int mat = z >> 3, e = z & 7;
    const float* in; int Rr, Cc;
    if (mat == 0)      { in = w1; Rr = D_MODEL; Cc = HIDDEN; }
    else if (mat == 1) { in = w3; Rr = D_MODEL; Cc = HIDDEN; }
    else               { in = w2; Rr = HIDDEN; Cc = D_MODEL; }
    const size_t eb_in = (size_t)e * Rr * Cc;
    const int ntc = Cc >> 7;
    const int c0 = (inner % ntc) * 128;
    const int r0 = (inner / ntc) * 64;

    const int c4 = tid & 31;
    const int rbase = tid >> 5;           // 0..7
    float4 v[8];
#pragma unroll
    for (int p = 0; p < 8; ++p) {
        int row = p * 8 + rbase;
        v[p] = *(const float4*)(in + eb_in + (size_t)(r0 + row) * Cc + c0 + c4 * 4);
    }
    const unsigned swz = (unsigned)((c4 & 7) << 2);
#pragma unroll
    for (int p = 0; p < 8; ++p) {
        int row = p * 8 + rbase;
        unsigned x01 = (unsigned)f2bf(v[p].x) | ((unsigned)f2bf(v[p].y) << 16);
        unsigned x23 = (unsigned)f2bf(v[p].z) | ((unsigned)f2bf(v[p].w) << 16);
        unsigned p01 = __shfl_xor(x01, 32, 64);
        unsigned p23 = __shfl_xor(x23, 32, 64);
        int rr = row >> 1;
        unsigned col = (unsigned)rr ^ swz;
        if ((row & 1) == 0) {
            tls[c4 * 4 + 0][col] = (x01 & 0xffffu) | (p01 << 16);
            tls[c4 * 4 + 1][col] = (x01 >> 16) | (p01 & 0xffff0000u);
        } else {
            tls[c4 * 4 + 2][col] = (p23 & 0xffffu) | (x23 << 16);
            tls[c4 * 4 + 3][col] = (p23 >> 16) | (x23 & 0xffff0000u);
        }
    }
    __syncthreads();

    if (mat < 2) {
        const size_t eb = (size_t)e * (2 * HIDDEN) * D_MODEL;
        const int moff = mat ? 16 : 0;
#pragma unroll
        for (int p = 0; p < 4; ++p) {
            int li = p * 256 + tid;
            int c = li >> 3;
            int j = li & 7;
            unsigned s2 = (unsigned)(((c >> 2) & 7) << 2);
            u32x4 d = *(const u32x4*)(&tls[c][(unsigned)(j * 4) ^ s2]);
            int C = c0 + c;
            int r13 = ((C >> 4) << 5) + moff + (C & 15);
            *(u32x4*)(&w13t[eb + (size_t)r13 * D_MODEL + r0 + j * 8]) = d;
        }
    } else {
        const size_t eb = (size_t)e * D_MODEL * HIDDEN;
#pragma unroll
        for (int p = 0; p < 4; ++p) {
            int li = p * 256 + tid;
            int c = li >> 3;
            int j = li & 7;
            unsigned s2 = (unsigned)(((c >> 2) & 7) << 2);
            u32x4 d = *(const u32x4*)(&tls[c][(unsigned)(j * 4) ^ s2]);
            *(u32x4*)(&w2t[eb + (size_t)(c0 + c) * HIDDEN + r0 + j * 8]) = d;
        }
    }
}

// ---------------- scan (padded to PADM) + scatter, single block ----------------
__global__ void k_scan_scatter(const int* __restrict__ counts,
                               const int* __restrict__ tok_e, const float* __restrict__ tok_w,
                               int* __restrict__ offs,
                               int* __restrict__ row_token, float* __restrict__ row_weight,
                               int* __restrict__ tok_pos, int T) {
    __shared__ int scurs[N_EXP];
    if (threadIdx.x == 0) {
        int s = 0;
        for (int e = 0; e < N_EXP; ++e) {
            offs[e] = s; scurs[e] = s;
            s += ((counts[e] + PADM - 1) / PADM) * PADM;
        }
        offs[N_EXP] = s;
    }
    __syncthreads();
    for (int i = threadIdx.x; i < 2 * T; i += blockDim.x) {
        int e = tok_e[i];
        int pos = atomicAdd(&scurs[e], 1);
        row_token[pos] = i >> 1;
        row_weight[pos] = tok_w[i];
        tok_pos[i] = pos;
    }
}

// ---------------- GEMM1: 128m x 256n, 4 waves, wave-tile 128x64, BK=32, 3-buf d2 ----------------
__global__ __launch_bounds__(256, 2) void k_gemm1(
    const unsigned short* __restrict__ xb,    // [T][D] bf16
    const unsigned short* __restrict__ w13t,  // [E][2H][D] bf16 interleaved
    const int* __restrict__ row_token,
    const float* __restrict__ row_weight,
    const int* __restrict__ offs,             // [E+1] 128-padded
    unsigned short* __restrict__ h)           // [Rp][H] bf16
{
    __shared__ unsigned short A[3][128 * BK];   // 3 x 8 KB
    __shared__ unsigned short B[3][256 * BK];   // 3 x 16 KB

    const int b = blockIdx.x;
    const int bs = (b & 7) * (G1X / 8) + (b >> 3);
    int e = 0, mt = 0, nt = 0, found = 0, at = 0;
#pragma unroll
    for (int ee = 0; ee < N_EXP; ++ee) {
        int me = (offs[ee + 1] - offs[ee]) >> 7;
        int te = me * 16;
        if (!found && bs < at + te) {
            int loc = bs - at;
            nt = loc / me;
            mt = loc - nt * me;
            e = ee; found = 1;
        }
        at += te;
    }
    if (!found) return;
    const int m0 = offs[e] + mt * 128;
    const int n0b = nt * 256;

    const int tid = threadIdx.x;
    const int lane = tid & 63, wn = tid >> 6;   // 4 waves, 1M x 4N

    // A staging: 2 chunks/thread (512 chunks of 16B)
    const unsigned short* asrc[2];
    unsigned aoff[2];
#pragma unroll
    for (int q = 0; q < 2; ++q) {
        int c = q * 256 + tid;
        int m = c >> 2, kc = c & 3;
        int kcs = kc ^ (m & 3);
        int tok = row_token[m0 + m];
        asrc[q] = xb + (size_t)tok * D_MODEL + kcs * 8;
        aoff[q] = (unsigned)c * 8u;
    }
    // B staging: 4 chunks/thread (1024 chunks)
    const unsigned short* bsrc[4];
    unsigned boff[4];
#pragma unroll
    for (int q = 0; q < 4; ++q) {
        int c = q * 256 + tid;
        int n = c >> 2, kc = c & 3;
        int kcs = kc ^ (n & 3);
        bsrc[q] = w13t + ((size_t)e * (2 * HIDDEN) + n0b + n) * D_MODEL + kcs * 8;
        boff[q] = (unsigned)c * 8u;
    }

    f32x4 acc[8][4];
    const f32x4 zf = {0.f, 0.f, 0.f, 0.f};
#pragma unroll
    for (int mi = 0; mi < 8; ++mi)
#pragma unroll
        for (int ni = 0; ni < 4; ++ni) acc[mi][ni] = zf;

    // prologue: stage tiles 0,1 (6 loads each)
#pragma unroll
    for (int t = 0; t < 2; ++t) {
        const int ko = t * BK;
        gload_lds16(asrc[0] + ko, &A[t][aoff[0]]);
        gload_lds16(asrc[1] + ko, &A[t][aoff[1]]);
        gload_lds16(bsrc[0] + ko, &B[t][boff[0]]);
        gload_lds16(bsrc[1] + ko, &B[t][boff[1]]);
        gload_lds16(bsrc[2] + ko, &B[t][boff[2]]);
        gload_lds16(bsrc[3] + ko, &B[t][boff[3]]);
    }

    int cur = 0;
#pragma unroll 1
    for (int kt = 0; kt < NT1; ++kt) {
        if (kt == NT1 - 1) asm volatile("s_waitcnt vmcnt(0)" ::: "memory");
        else               asm volatile("s_waitcnt vmcnt(6)" ::: "memory");
        __builtin_amdgcn_s_barrier();

        const unsigned short* Ac = &A[cur][0];
        const unsigned short* Bc = &B[cur][0];
        const int nb = (cur + 2 >= 3) ? (cur - 1) : (cur + 2);
        const int ko = (kt + 2) * BK;
        const bool pf = (kt + 2 < NT1);

        bf16x8 a[8], bf[4];
        const int ke = (lane >> 4) * 8;
#pragma unroll
        for (int mi = 0; mi < 8; ++mi) {
            int m = mi * 16 + (lane & 15);
            a[mi] = *(const bf16x8*)(&Ac[m * BK + (ke ^ ((m & 3) * 8))]);
        }
#pragma unroll
        for (int ni = 0; ni < 4; ++ni) {
            int n = wn * 64 + ni * 16 + (lane & 15);
            bf[ni] = *(const bf16x8*)(&Bc[n * BK + (ke ^ ((n & 3) * 8))]);
        }
        if (pf) {
            gload_lds16(asrc[0] + ko, &A[nb][aoff[0]]);
            gload_lds16(asrc[1] + ko, &A[nb][aoff[1]]);
            gload_lds16(bsrc[0] + ko, &B[nb][boff[0]]);
            gload_lds16(bsrc[1] + ko, &B[nb][boff[1]]);
            gload_lds16(bsrc[2] + ko, &B[nb][boff[2]]);
            gload_lds16(bsrc[3] + ko, &B[nb][boff[3]]);
        }
        __builtin_amdgcn_s_barrier();
        __builtin_amdgcn_s_setprio(1);
#pragma unroll
        for (int mi = 0; mi < 8; ++mi)
#pragma unroll
            for (int ni = 0; ni < 4; ++ni)
                acc[mi][ni] = __builtin_amdgcn_mfma_f32_16x16x32_bf16(a[mi], bf[ni], acc[mi][ni], 0, 0, 0);
        __builtin_amdgcn_s_setprio(0);
        cur = (cur == 2) ? 0 : (cur + 1);
    }

    // epilogue: silu(acc[.][even]) * acc[.][odd] -> h
    const int g0 = (n0b + wn * 64) >> 5;
#pragma unroll
    for (int mi = 0; mi < 8; ++mi) {
#pragma unroll
        for (int r = 0; r < 4; ++r) {
            int m = mi * 16 + (lane >> 4) * 4 + r;
            float wgt = row_weight[m0 + m];
            size_t rowbase = (size_t)(m0 + m) * HIDDEN;
#pragma unroll
            for (int p = 0; p < 2; ++p) {
                float v1 = acc[mi][2 * p][r], v3 = acc[mi][2 * p + 1][r];
                float sv = v1 / (1.f + __expf(-v1));
                int hc = (g0 + p) * 16 + (lane & 15);
                h[rowbase + hc] = f2bf(sv * v3 * wgt);
            }
        }
    }
}

// ---------------- GEMM2: 128m x 256n, same schedule, BK=32 ----------------
__global__ __launch_bounds__(256, 2) void k_gemm2(
    const unsigned short* __restrict__ hh,   // [Rp][H] bf16
    const unsigned short* __restrict__ w2t,  // [E][D][H] bf16
    const int* __restrict__ offs,
    unsigned short* __restrict__ y)          // [Rp][D] bf16
{
    __shared__ unsigned short A[3][128 * BK];   // 3 x 8 KB
    __shared__ unsigned short B[3][256 * BK];   // 3 x 16 KB

    const int b = blockIdx.x;
    const int bs = (b & 7) * (G2X / 8) + (b >> 3);
    int e = 0, mt = 0, nt = 0, found = 0, at = 0;
#pragma unroll
    for (int ee = 0; ee < N_EXP; ++ee) {
        int me = (offs[ee + 1] - offs[ee]) >> 7;
        int te = me * 4;
        if (!found && bs < at + te) {
            int loc = bs - at;
            nt = loc / me;
            mt = loc - nt * me;
            e = ee; found = 1;
        }
        at += te;
    }
    if (!found) return;
    const int m0 = offs[e] + mt * 128;
    const int n0 = nt * 256;

    const int tid = threadIdx.x;
    const int lane = tid & 63, wn = tid >> 6;

    const unsigned short* asrc[2];
    unsigned aoff[2];
#pragma unroll
    for (int q = 0; q < 2; ++q) {
        int c = q * 256 + tid;
        int m = c >> 2, kc = c & 3;
        int kcs = kc ^ (m & 3);
        asrc[q] = hh + (size_t)(m0 + m) * HIDDEN + kcs * 8;
        aoff[q] = (unsigned)c * 8u;
    }
    const unsigned short* bsrc[4];
    unsigned boff[4];
#pragma unroll
    for (int q = 0; q < 4; ++q) {
        int c = q * 256 + tid;
        int n = c >> 2, kc = c & 3;
        int kcs = kc ^ (n & 3);
        bsrc[q] = w2t + ((size_t)e * D_MODEL + n0 + n) * HIDDEN + kcs * 8;
        boff[q] = (unsigned)c * 8u;
    }

    f32x4 acc[8][4];
    const f32x4 zf = {0.f, 0.f, 0.f, 0.f};
#pragma unroll
    for (int mi = 0; mi < 8; ++mi)
#pragma unroll
        for (int ni = 0; ni < 4; ++ni) acc[mi][ni] = zf;

#pragma unroll
    for (int t = 0; t < 2; ++t) {
        const int ko = t * BK;
        gload_lds16(asrc[0] + ko, &A[t][aoff[0]]);
        gload_lds16(asrc[1] + ko, &A[t][aoff[1]]);
        gload_lds16(bsrc[0] + ko, &B[t][boff[0]]);
        gload_lds16(bsrc[1] + ko, &B[t][boff[1]]);
        gload_lds16(bsrc[2] + ko, &B[t][boff[2]]);
        gload_lds16(bsrc[3] + ko, &B[t][boff[3]]);
    }

    int cur = 0;
#pragma unroll 1
    for (int kt = 0; kt < NT2; ++kt) {
        if (kt == NT2 - 1) asm volatile("s_waitcnt vmcnt(0)" ::: "memory");
        else               asm volatile("s_waitcnt vmcnt(6)" ::: "memory");
        __builtin_amdgcn_s_barrier();

        const unsigned short* Ac = &A[cur][0];
        const unsigned short* Bc = &B[cur][0];
        const int nb = (cur + 2 >= 3) ? (cur - 1) : (cur + 2);
        const int ko = (kt + 2) * BK;
        const bool pf = (kt + 2 < NT2);

        bf16x8 a[8], bf[4];
        const int ke = (lane >> 4) * 8;
#pragma unroll
        for (int mi = 0; mi < 8; ++mi) {
            int m = mi * 16 + (lane & 15);
            a[mi] = *(const bf16x8*)(&Ac[m * BK + (ke ^ ((m & 3) * 8))]);
        }
#pragma unroll
        for (int ni = 0; ni < 4; ++ni) {
            int n = wn * 64 + ni * 16 + (lane & 15);
            bf[ni] = *(const bf16x8*)(&Bc[n * BK + (ke ^ ((n & 3) * 8))]);
        }
        if (pf) {
            gload_lds16(asrc[0] + ko, &A[nb][aoff[0]]);
            gload_lds16(asrc[1] + ko, &A[nb][aoff[1]]);
            gload_lds16(bsrc[0] + ko, &B[nb][boff[0]]);
            gload_lds16(bsrc[1] + ko, &B[nb][boff[1]]);
            gload_lds16(bsrc[2] + ko, &B[nb][boff[2]]);
            gload_lds16(bsrc[3] + ko, &B[nb][boff[3]]);
        }
        __builtin_amdgcn_s_barrier();
        __builtin_amdgcn_s_setprio(1);
#pragma unroll
        for (int mi = 0; mi < 8; ++mi)
#pragma unroll
            for (int ni = 0; ni < 4; ++ni)
                acc[mi][ni] = __builtin_amdgcn_mfma_f32_16x16x32_bf16(a[mi], bf[ni], acc[mi][ni], 0, 0, 0);
        __builtin_amdgcn_s_setprio(0);
        cur = (cur == 2) ? 0 : (cur + 1);
    }

#pragma unroll
    for (int mi = 0; mi < 8; ++mi) {
#pragma unroll
        for (int r = 0; r < 4; ++r) {
            int m = mi * 16 + (lane >> 4) * 4 + r;
            size_t rowbase = (size_t)(m0 + m) * D_MODEL + n0;
#pragma unroll
            for (int ni = 0; ni < 4; ++ni) {
                int n = wn * 64 + ni * 16 + (lane & 15);
                y[rowbase + n] = f2bf(acc[mi][ni][r]);
            }
        }
    }
}

// ---------------- combine: out[t] = y[pos0] + y[pos1] ----------------
__global__ void k_combine(const unsigned short* __restrict__ y,
                          const int* __restrict__ tok_pos,
                          float* __restrict__ out, int n8) {
    int i = blockIdx.x * blockDim.x + threadIdx.x;
    if (i >= n8) return;
    int t = i >> 7;
    int c = (i & 127) * 8;
    int p0 = tok_pos[2 * t];
    int p1 = tok_pos[2 * t + 1];
    bf16x8 v0 = *(const bf16x8*)(y + (size_t)p0 * D_MODEL + c);
    bf16x8 v1 = *(const bf16x8*)(y + (size_t)p1 * D_MODEL + c);
    float* op = out + (size_t)t * D_MODEL + c;
    float4 o0, o1;
    o0.x = bf2f((unsigned short)v0[0]) + bf2f((unsigned short)v1[0]);
    o0.y = bf2f((unsigned short)v0[1]) + bf2f((unsigned short)v1[1]);
    o0.z = bf2f((unsigned short)v0[2]) + bf2f((unsigned short)v1[2]);
    o0.w = bf2f((unsigned short)v0[3]) + bf2f((unsigned short)v1[3]);
    o1.x = bf2f((unsigned short)v0[4]) + bf2f((unsigned short)v1[4]);
    o1.y = bf2f((unsigned short)v0[5]) + bf2f((unsigned short)v1[5]);
    o1.z = bf2f((unsigned short)v0[6]) + bf2f((unsigned short)v1[6]);
    o1.w = bf2f((unsigned short)v0[7]) + bf2f((unsigned short)v1[7]);
    *(float4*)op = o0;
    *(float4*)(op + 4) = o1;
}

extern "C" void kernel_launch(void* const* d_in, const int* in_sizes, int n_in,
                              void* d_out, int out_size, void* d_ws, size_t ws_size,
                              hipStream_t stream) {
    const float* x  = (const float*)d_in[0];
    const float* wr = (const float*)d_in[1];
    const float* w1 = (const float*)d_in[2];
    const float* w3 = (const float*)d_in[3];
    const float* w2 = (const float*)d_in[4];
    float* out = (float*)d_out;

    const int T = in_sizes[0] / D_MODEL;    // 4096
    const int Rp = T * TOPK + N_EXP * PADM; // 9216

    char* ws = (char*)d_ws;
    size_t o = 0;
    unsigned short* xb   = (unsigned short*)(ws + o); o += (size_t)T * D_MODEL * 2;
    unsigned short* h    = (unsigned short*)(ws + o); o += (size_t)Rp * HIDDEN * 2;
    unsigned short* w13t = (unsigned short*)(ws + o); o += (size_t)N_EXP * 2 * HIDDEN * D_MODEL * 2;
    unsigned short* w2t  = (unsigned short*)(ws + o); o += (size_t)N_EXP * D_MODEL * HIDDEN * 2;
    int*   row_token  = (int*)(ws + o);   o += (size_t)Rp * 4;
    float* row_weight = (float*)(ws + o); o += (size_t)Rp * 4;
    int*   tok_e      = (int*)(ws + o);   o += (size_t)2 * T * 4;
    float* tok_w      = (float*)(ws + o); o += (size_t)2 * T * 4;
    int*   tok_pos    = (int*)(ws + o);   o += (size_t)2 * T * 4;
    int*   counts     = (int*)(ws + o);   o += 16 * 4;
    int*   offs       = (int*)(ws + o);   o += 16 * 4;

    // y aliases w13t (dead after gemm1)
    unsigned short* y = w13t;

    hipMemsetAsync(counts, 0, 16 * 4, stream);
    hipMemsetAsync(row_token, 0, (size_t)Rp * 4, stream);
    hipMemsetAsync(row_weight, 0, (size_t)Rp * 4, stream);

    const int nrouter = (T + 3) / 4;            // 1024
    const int nprep = nrouter + 6144;           // + transpose blocks ([64r][128c] tiles)
    k_prep<<<nprep, 256, 0, stream>>>(x, wr, w1, w3, w2, xb, w13t, w2t,
                                      tok_e, tok_w, counts, T, nrouter);

    k_scan_scatter<<<1, 1024, 0, stream>>>(counts, tok_e, tok_w, offs,
                                           row_token, row_weight, tok_pos, T);

    k_gemm1<<<G1X, 256, 0, stream>>>(xb, w13t, row_token, row_weight, offs, h);
    k_gemm2<<<G2X, 256, 0, stream>>>(h, w2t, offs, y);

    int n8 = T * D_MODEL / 8;
    k_combine<<<(n8 + 255) / 256, 256, 0, stream>>>(y, tok_pos, out, n8);
}

// Round 17
// 305.011 us; speedup vs baseline: 1.7042x; 1.0093x over previous
//
#include <hip/hip_runtime.h>
#include <stdint.h>

#define D_MODEL 1024
#define N_EXP   8
#define HIDDEN  2048
#define TOPK    2

#define BK    32
#define PADM  128
#define NT1   (D_MODEL / BK)   // 32
#define NT2   (HIDDEN / BK)    // 64
#define G1X   1152             // 72 m-tiles(128) x 16 n-tiles(256 of 2H)
#define G2X   288              // 72 m-tiles(128) x 4 n-tiles(256 of D)

typedef short bf16x8 __attribute__((ext_vector_type(8)));
typedef float f32x4 __attribute__((ext_vector_type(4)));
typedef unsigned u32x4 __attribute__((ext_vector_type(4)));

__device__ __forceinline__ unsigned short f2bf(float f) {
    union { float f; unsigned u; } v; v.f = f;
    unsigned r = v.u + 0x7fffu + ((v.u >> 16) & 1u);
    return (unsigned short)(r >> 16);
}

__device__ __forceinline__ float bf2f(unsigned short u) {
    union { unsigned u; float f; } v; v.u = (unsigned)u << 16; return v.f;
}

__device__ __forceinline__ void gload_lds16(const void* g, void* l) {
    __builtin_amdgcn_global_load_lds(
        (const __attribute__((address_space(1))) void*)g,
        (__attribute__((address_space(3))) void*)l, 16, 0, 0);
}

// ---------------- fused prep (R11-exact): router + x->bf16 AND weight transpose ----------------
__global__ __launch_bounds__(256) void k_prep(
    const float* __restrict__ x, const float* __restrict__ wr,
    const float* __restrict__ w1, const float* __restrict__ w3, const float* __restrict__ w2,
    unsigned short* __restrict__ xb,
    unsigned short* __restrict__ w13t, unsigned short* __restrict__ w2t,
    int* __restrict__ tok_e, float* __restrict__ tok_w,
    int* __restrict__ counts, int T, int nrouter)
{
    __shared__ unsigned tls[128][32];     // 16 KB
    const int bx = blockIdx.x;
    const int tid = threadIdx.x;

    if (bx < nrouter) {
        int t = bx * 4 + (tid >> 6);
        int lane = tid & 63;
        if (t >= T) return;
        const float4* xr = (const float4*)(x + (size_t)t * D_MODEL);
        float acc[N_EXP];
#pragma unroll
        for (int e = 0; e < N_EXP; ++e) acc[e] = 0.f;
#pragma unroll
        for (int j = 0; j < 4; ++j) {
            int c = j * 64 + lane;
            float4 v = xr[c];
            ushort4 pk;
            pk.x = f2bf(v.x); pk.y = f2bf(v.y); pk.z = f2bf(v.z); pk.w = f2bf(v.w);
            *(ushort4*)(xb + (size_t)t * D_MODEL + c * 4) = pk;
            const float4* w4 = (const float4*)(wr + (size_t)c * 4 * N_EXP);
#pragma unroll
            for (int k = 0; k < 4; ++k) {
                float xv = (k == 0) ? v.x : (k == 1) ? v.y : (k == 2) ? v.z : v.w;
                float4 wa = w4[k * 2], wb = w4[k * 2 + 1];
                acc[0] += xv * wa.x; acc[1] += xv * wa.y; acc[2] += xv * wa.z; acc[3] += xv * wa.w;
                acc[4] += xv * wb.x; acc[5] += xv * wb.y; acc[6] += xv * wb.z; acc[7] += xv * wb.w;
            }
        }
#pragma unroll
        for (int off = 32; off > 0; off >>= 1) {
#pragma unroll
            for (int e = 0; e < N_EXP; ++e) acc[e] += __shfl_down(acc[e], off, 64);
        }
        if (lane == 0) {
            float mx = acc[0];
#pragma unroll
            for (int e = 1; e < N_EXP; ++e) mx = fmaxf(mx, acc[e]);
            float p[N_EXP], den = 0.f;
#pragma unroll
            for (int e = 0; e < N_EXP; ++e) { p[e] = __expf(acc[e] - mx); den += p[e]; }
            float inv = 1.f / den;
            int e0 = 0; float v0 = acc[0];
#pragma unroll
            for (int e = 1; e < N_EXP; ++e) if (acc[e] > v0) { v0 = acc[e]; e0 = e; }
            int e1 = -1; float v1 = -1e30f;
#pragma unroll
            for (int e = 0; e < N_EXP; ++e) if (e != e0 && acc[e] > v1) { v1 = acc[e]; e1 = e; }
            tok_e[2 * t] = e0;     tok_w[2 * t] = p[e0] * inv;
            tok_e[2 * t + 1] = e1; tok_w[2 * t + 1] = p[e1] * inv;
            atomicAdd(&counts[e0], 1);
            atomicAdd(&counts[e1], 1);
        }
        return;
    }

    // ---- weight convert + transpose, [64 r][128 c] tile ----
    const int b2 = bx - nrouter;          // 0..6143
    const int z = b2 >> 8;                // 0..23
    const int inner = b2 & 255;
    const int mat = z >> 3, e = z & 7;
    const float* in; int Rr, Cc;
    if (mat == 0)      { in = w1; Rr = D_MODEL; Cc = HIDDEN; }
    else if (mat == 1) { in = w3; Rr = D_MODEL; Cc = HIDDEN; }
    else               { in = w2; Rr = HIDDEN; Cc = D_MODEL; }
    const size_t eb_in = (size_t)e * Rr * Cc;
    const int ntc = Cc >> 7;
    const int c0 = (inner % ntc) * 128;
    const int r0 = (inner / ntc) * 64;

    const int c4 = tid & 31;
    const int rbase = tid >> 5;           // 0..7
    float4 v[8];
#pragma unroll
    for (int p = 0; p < 8; ++p) {
        int row = p * 8 + rbase;
        v[p] = *(const float4*)(in + eb_in + (size_t)(r0 + row) * Cc + c0 + c4 * 4);
    }
    const unsigned swz = (unsigned)((c4 & 7) << 2);
#pragma unroll
    for (int p = 0; p < 8; ++p) {
        int row = p * 8 + rbase;
        unsigned x01 = (unsigned)f2bf(v[p].x) | ((unsigned)f2bf(v[p].y) << 16);
        unsigned x23 = (unsigned)f2bf(v[p].z) | ((unsigned)f2bf(v[p].w) << 16);
        unsigned p01 = __shfl_xor(x01, 32, 64);
        unsigned p23 = __shfl_xor(x23, 32, 64);
        int rr = row >> 1;
        unsigned col = (unsigned)rr ^ swz;
        if ((row & 1) == 0) {
            tls[c4 * 4 + 0][col] = (x01 & 0xffffu) | (p01 << 16);
            tls[c4 * 4 + 1][col] = (x01 >> 16) | (p01 & 0xffff0000u);
        } else {
            tls[c4 * 4 + 2][col] = (p23 & 0xffffu) | (x23 << 16);
            tls[c4 * 4 + 3][col] = (p23 >> 16) | (x23 & 0xffff0000u);
        }
    }
    __syncthreads();

    if (mat < 2) {
        const size_t eb = (size_t)e * (2 * HIDDEN) * D_MODEL;
        const int moff = mat ? 16 : 0;
#pragma unroll
        for (int p = 0; p < 4; ++p) {
            int li = p * 256 + tid;
            int c = li >> 3;
            int j = li & 7;
            unsigned s2 = (unsigned)(((c >> 2) & 7) << 2);
            u32x4 d = *(const u32x4*)(&tls[c][(unsigned)(j * 4) ^ s2]);
            int C = c0 + c;
            int r13 = ((C >> 4) << 5) + moff + (C & 15);
            *(u32x4*)(&w13t[eb + (size_t)r13 * D_MODEL + r0 + j * 8]) = d;
        }
    } else {
        const size_t eb = (size_t)e * D_MODEL * HIDDEN;
#pragma unroll
        for (int p = 0; p < 4; ++p) {
            int li = p * 256 + tid;
            int c = li >> 3;
            int j = li & 7;
            unsigned s2 = (unsigned)(((c >> 2) & 7) << 2);
            u32x4 d = *(const u32x4*)(&tls[c][(unsigned)(j * 4) ^ s2]);
            *(u32x4*)(&w2t[eb + (size_t)(c0 + c) * HIDDEN + r0 + j * 8]) = d;
        }
    }
}

// ---------------- scan (padded to PADM) + scatter, single block ----------------
__global__ void k_scan_scatter(const int* __restrict__ counts,
                               const int* __restrict__ tok_e, const float* __restrict__ tok_w,
                               int* __restrict__ offs,
                               int* __restrict__ row_token, float* __restrict__ row_weight,
                               int* __restrict__ tok_pos, int T) {
    __shared__ int scurs[N_EXP];
    if (threadIdx.x == 0) {
        int s = 0;
        for (int e = 0; e < N_EXP; ++e) {
            offs[e] = s; scurs[e] = s;
            s += ((counts[e] + PADM - 1) / PADM) * PADM;
        }
        offs[N_EXP] = s;
    }
    __syncthreads();
    for (int i = threadIdx.x; i < 2 * T; i += blockDim.x) {
        int e = tok_e[i];
        int pos = atomicAdd(&scurs[e], 1);
        row_token[pos] = i >> 1;
        row_weight[pos] = tok_w[i];
        tok_pos[i] = pos;
    }
}

// ---------------- GEMM1: 128m x 256n, 4 waves, wave-tile 128x64, BK=32, 3-buf d2 ----------------
__global__ __launch_bounds__(256, 2) void k_gemm1(
    const unsigned short* __restrict__ xb,    // [T][D] bf16
    const unsigned short* __restrict__ w13t,  // [E][2H][D] bf16 interleaved
    const int* __restrict__ row_token,
    const float* __restrict__ row_weight,
    const int* __restrict__ offs,             // [E+1] 128-padded
    unsigned short* __restrict__ h)           // [Rp][H] bf16
{
    __shared__ unsigned short A[3][128 * BK];   // 3 x 8 KB
    __shared__ unsigned short B[3][256 * BK];   // 3 x 16 KB

    const int b = blockIdx.x;
    const int bs = (b & 7) * (G1X / 8) + (b >> 3);
    int e = 0, mt = 0, nt = 0, found = 0, at = 0;
#pragma unroll
    for (int ee = 0; ee < N_EXP; ++ee) {
        int me = (offs[ee + 1] - offs[ee]) >> 7;
        int te = me * 16;
        if (!found && bs < at + te) {
            int loc = bs - at;
            nt = loc / me;
            mt = loc - nt * me;
            e = ee; found = 1;
        }
        at += te;
    }
    if (!found) return;
    const int m0 = offs[e] + mt * 128;
    const int n0b = nt * 256;

    const int tid = threadIdx.x;
    const int lane = tid & 63, wn = tid >> 6;   // 4 waves, 1M x 4N

    // A staging: 2 chunks/thread (512 chunks of 16B)
    const unsigned short* asrc[2];
    unsigned aoff[2];
#pragma unroll
    for (int q = 0; q < 2; ++q) {
        int c = q * 256 + tid;
        int m = c >> 2, kc = c & 3;
        int kcs = kc ^ (m & 3);
        int tok = row_token[m0 + m];
        asrc[q] = xb + (size_t)tok * D_MODEL + kcs * 8;
        aoff[q] = (unsigned)c * 8u;
    }
    // B staging: 4 chunks/thread (1024 chunks)
    const unsigned short* bsrc[4];
    unsigned boff[4];
#pragma unroll
    for (int q = 0; q < 4; ++q) {
        int c = q * 256 + tid;
        int n = c >> 2, kc = c & 3;
        int kcs = kc ^ (n & 3);
        bsrc[q] = w13t + ((size_t)e * (2 * HIDDEN) + n0b + n) * D_MODEL + kcs * 8;
        boff[q] = (unsigned)c * 8u;
    }

    f32x4 acc[8][4];
    const f32x4 zf = {0.f, 0.f, 0.f, 0.f};
#pragma unroll
    for (int mi = 0; mi < 8; ++mi)
#pragma unroll
        for (int ni = 0; ni < 4; ++ni) acc[mi][ni] = zf;

    // prologue: stage tiles 0,1 (6 loads each)
#pragma unroll
    for (int t = 0; t < 2; ++t) {
        const int ko = t * BK;
        gload_lds16(asrc[0] + ko, &A[t][aoff[0]]);
        gload_lds16(asrc[1] + ko, &A[t][aoff[1]]);
        gload_lds16(bsrc[0] + ko, &B[t][boff[0]]);
        gload_lds16(bsrc[1] + ko, &B[t][boff[1]]);
        gload_lds16(bsrc[2] + ko, &B[t][boff[2]]);
        gload_lds16(bsrc[3] + ko, &B[t][boff[3]]);
    }

    int cur = 0;
#pragma unroll 1
    for (int kt = 0; kt < NT1; ++kt) {
        if (kt == NT1 - 1) asm volatile("s_waitcnt vmcnt(0)" ::: "memory");
        else               asm volatile("s_waitcnt vmcnt(6)" ::: "memory");
        __builtin_amdgcn_s_barrier();

        const unsigned short* Ac = &A[cur][0];
        const unsigned short* Bc = &B[cur][0];
        const int nb = (cur + 2 >= 3) ? (cur - 1) : (cur + 2);
        const int ko = (kt + 2) * BK;
        const bool pf = (kt + 2 < NT1);

        bf16x8 a[8], bf[4];
        const int ke = (lane >> 4) * 8;
#pragma unroll
        for (int mi = 0; mi < 8; ++mi) {
            int m = mi * 16 + (lane & 15);
            a[mi] = *(const bf16x8*)(&Ac[m * BK + (ke ^ ((m & 3) * 8))]);
        }
#pragma unroll
        for (int ni = 0; ni < 4; ++ni) {
            int n = wn * 64 + ni * 16 + (lane & 15);
            bf[ni] = *(const bf16x8*)(&Bc[n * BK + (ke ^ ((n & 3) * 8))]);
        }
        if (pf) {
            gload_lds16(asrc[0] + ko, &A[nb][aoff[0]]);
            gload_lds16(asrc[1] + ko, &A[nb][aoff[1]]);
            gload_lds16(bsrc[0] + ko, &B[nb][boff[0]]);
            gload_lds16(bsrc[1] + ko, &B[nb][boff[1]]);
            gload_lds16(bsrc[2] + ko, &B[nb][boff[2]]);
            gload_lds16(bsrc[3] + ko, &B[nb][boff[3]]);
        }
        __builtin_amdgcn_s_barrier();
        __builtin_amdgcn_s_setprio(1);
#pragma unroll
        for (int mi = 0; mi < 8; ++mi)
#pragma unroll
            for (int ni = 0; ni < 4; ++ni)
                acc[mi][ni] = __builtin_amdgcn_mfma_f32_16x16x32_bf16(a[mi], bf[ni], acc[mi][ni], 0, 0, 0);
        __builtin_amdgcn_s_setprio(0);
        cur = (cur == 2) ? 0 : (cur + 1);
    }

    // epilogue: silu(acc[.][even]) * acc[.][odd] -> h
    const int g0 = (n0b + wn * 64) >> 5;
#pragma unroll
    for (int mi = 0; mi < 8; ++mi) {
#pragma unroll
        for (int r = 0; r < 4; ++r) {
            int m = mi * 16 + (lane >> 4) * 4 + r;
            float wgt = row_weight[m0 + m];
            size_t rowbase = (size_t)(m0 + m) * HIDDEN;
#pragma unroll
            for (int p = 0; p < 2; ++p) {
                float v1 = acc[mi][2 * p][r], v3 = acc[mi][2 * p + 1][r];
                float sv = v1 / (1.f + __expf(-v1));
                int hc = (g0 + p) * 16 + (lane & 15);
                h[rowbase + hc] = f2bf(sv * v3 * wgt);
            }
        }
    }
}

// ---------------- GEMM2: 128m x 256n, same schedule, BK=32 ----------------
__global__ __launch_bounds__(256, 2) void k_gemm2(
    const unsigned short* __restrict__ hh,   // [Rp][H] bf16
    const unsigned short* __restrict__ w2t,  // [E][D][H] bf16
    const int* __restrict__ offs,
    unsigned short* __restrict__ y)          // [Rp][D] bf16
{
    __shared__ unsigned short A[3][128 * BK];   // 3 x 8 KB
    __shared__ unsigned short B[3][256 * BK];   // 3 x 16 KB

    const int b = blockIdx.x;
    const int bs = (b & 7) * (G2X / 8) + (b >> 3);
    int e = 0, mt = 0, nt = 0, found = 0, at = 0;
#pragma unroll
    for (int ee = 0; ee < N_EXP; ++ee) {
        int me = (offs[ee + 1] - offs[ee]) >> 7;
        int te = me * 4;
        if (!found && bs < at + te) {
            int loc = bs - at;
            nt = loc / me;
            mt = loc - nt * me;
            e = ee; found = 1;
        }
        at += te;
    }
    if (!found) return;
    const int m0 = offs[e] + mt * 128;
    const int n0 = nt * 256;

    const int tid = threadIdx.x;
    const int lane = tid & 63, wn = tid >> 6;

    const unsigned short* asrc[2];
    unsigned aoff[2];
#pragma unroll
    for (int q = 0; q < 2; ++q) {
        int c = q * 256 + tid;
        int m = c >> 2, kc = c & 3;
        int kcs = kc ^ (m & 3);
        asrc[q] = hh + (size_t)(m0 + m) * HIDDEN + kcs * 8;
        aoff[q] = (unsigned)c * 8u;
    }
    const unsigned short* bsrc[4];
    unsigned boff[4];
#pragma unroll
    for (int q = 0; q < 4; ++q) {
        int c = q * 256 + tid;
        int n = c >> 2, kc = c & 3;
        int kcs = kc ^ (n & 3);
        bsrc[q] = w2t + ((size_t)e * D_MODEL + n0 + n) * HIDDEN + kcs * 8;
        boff[q] = (unsigned)c * 8u;
    }

    f32x4 acc[8][4];
    const f32x4 zf = {0.f, 0.f, 0.f, 0.f};
#pragma unroll
    for (int mi = 0; mi < 8; ++mi)
#pragma unroll
        for (int ni = 0; ni < 4; ++ni) acc[mi][ni] = zf;

#pragma unroll
    for (int t = 0; t < 2; ++t) {
        const int ko = t * BK;
        gload_lds16(asrc[0] + ko, &A[t][aoff[0]]);
        gload_lds16(asrc[1] + ko, &A[t][aoff[1]]);
        gload_lds16(bsrc[0] + ko, &B[t][boff[0]]);
        gload_lds16(bsrc[1] + ko, &B[t][boff[1]]);
        gload_lds16(bsrc[2] + ko, &B[t][boff[2]]);
        gload_lds16(bsrc[3] + ko, &B[t][boff[3]]);
    }

    int cur = 0;
#pragma unroll 1
    for (int kt = 0; kt < NT2; ++kt) {
        if (kt == NT2 - 1) asm volatile("s_waitcnt vmcnt(0)" ::: "memory");
        else               asm volatile("s_waitcnt vmcnt(6)" ::: "memory");
        __builtin_amdgcn_s_barrier();

        const unsigned short* Ac = &A[cur][0];
        const unsigned short* Bc = &B[cur][0];
        const int nb = (cur + 2 >= 3) ? (cur - 1) : (cur + 2);
        const int ko = (kt + 2) * BK;
        const bool pf = (kt + 2 < NT2);

        bf16x8 a[8], bf[4];
        const int ke = (lane >> 4) * 8;
#pragma unroll
        for (int mi = 0; mi < 8; ++mi) {
            int m = mi * 16 + (lane & 15);
            a[mi] = *(const bf16x8*)(&Ac[m * BK + (ke ^ ((m & 3) * 8))]);
        }
#pragma unroll
        for (int ni = 0; ni < 4; ++ni) {
            int n = wn * 64 + ni * 16 + (lane & 15);
            bf[ni] = *(const bf16x8*)(&Bc[n * BK + (ke ^ ((n & 3) * 8))]);
        }
        if (pf) {
            gload_lds16(asrc[0] + ko, &A[nb][aoff[0]]);
            gload_lds16(asrc[1] + ko, &A[nb][aoff[1]]);
            gload_lds16(bsrc[0] + ko, &B[nb][boff[0]]);
            gload_lds16(bsrc[1] + ko, &B[nb][boff[1]]);
            gload_lds16(bsrc[2] + ko, &B[nb][boff[2]]);
            gload_lds16(bsrc[3] + ko, &B[nb][boff[3]]);
        }
        __builtin_amdgcn_s_barrier();
        __builtin_amdgcn_s_setprio(1);
#pragma unroll
        for (int mi = 0; mi < 8; ++mi)
#pragma unroll
            for (int ni = 0; ni < 4; ++ni)
                acc[mi][ni] = __builtin_amdgcn_mfma_f32_16x16x32_bf16(a[mi], bf[ni], acc[mi][ni], 0, 0, 0);
        __builtin_amdgcn_s_setprio(0);
        cur = (cur == 2) ? 0 : (cur + 1);
    }

#pragma unroll
    for (int mi = 0; mi < 8; ++mi) {
#pragma unroll
        for (int r = 0; r < 4; ++r) {
            int m = mi * 16 + (lane >> 4) * 4 + r;
            size_t rowbase = (size_t)(m0 + m) * D_MODEL + n0;
#pragma unroll
            for (int ni = 0; ni < 4; ++ni) {
                int n = wn * 64 + ni * 16 + (lane & 15);
                y[rowbase + n] = f2bf(acc[mi][ni][r]);
            }
        }
    }
}

// ---------------- combine: out[t] = y[pos0] + y[pos1] ----------------
__global__ void k_combine(const unsigned short* __restrict__ y,
                          const int* __restrict__ tok_pos,
                          float* __restrict__ out, int n8) {
    int i = blockIdx.x * blockDim.x + threadIdx.x;
    if (i >= n8) return;
    int t = i >> 7;
    int c = (i & 127) * 8;
    int p0 = tok_pos[2 * t];
    int p1 = tok_pos[2 * t + 1];
    bf16x8 v0 = *(const bf16x8*)(y + (size_t)p0 * D_MODEL + c);
    bf16x8 v1 = *(const bf16x8*)(y + (size_t)p1 * D_MODEL + c);
    float* op = out + (size_t)t * D_MODEL + c;
    float4 o0, o1;
    o0.x = bf2f((unsigned short)v0[0]) + bf2f((unsigned short)v1[0]);
    o0.y = bf2f((unsigned short)v0[1]) + bf2f((unsigned short)v1[1]);
    o0.z = bf2f((unsigned short)v0[2]) + bf2f((unsigned short)v1[2]);
    o0.w = bf2f((unsigned short)v0[3]) + bf2f((unsigned short)v1[3]);
    o1.x = bf2f((unsigned short)v0[4]) + bf2f((unsigned short)v1[4]);
    o1.y = bf2f((unsigned short)v0[5]) + bf2f((unsigned short)v1[5]);
    o1.z = bf2f((unsigned short)v0[6]) + bf2f((unsigned short)v1[6]);
    o1.w = bf2f((unsigned short)v0[7]) + bf2f((unsigned short)v1[7]);
    *(float4*)op = o0;
    *(float4*)(op + 4) = o1;
}

extern "C" void kernel_launch(void* const* d_in, const int* in_sizes, int n_in,
                              void* d_out, int out_size, void* d_ws, size_t ws_size,
                              hipStream_t stream) {
    const float* x  = (const float*)d_in[0];
    const float* wr = (const float*)d_in[1];
    const float* w1 = (const float*)d_in[2];
    const float* w3 = (const float*)d_in[3];
    const float* w2 = (const float*)d_in[4];
    float* out = (float*)d_out;

    const int T = in_sizes[0] / D_MODEL;    // 4096
    const int Rp = T * TOPK + N_EXP * PADM; // 9216

    char* ws = (char*)d_ws;
    size_t o = 0;
    unsigned short* xb   = (unsigned short*)(ws + o); o += (size_t)T * D_MODEL * 2;
    unsigned short* h    = (unsigned short*)(ws + o); o += (size_t)Rp * HIDDEN * 2;
    unsigned short* w13t = (unsigned short*)(ws + o); o += (size_t)N_EXP * 2 * HIDDEN * D_MODEL * 2;
    unsigned short* w2t  = (unsigned short*)(ws + o); o += (size_t)N_EXP * D_MODEL * HIDDEN * 2;
    int*   row_token  = (int*)(ws + o);   o += (size_t)Rp * 4;
    float* row_weight = (float*)(ws + o); o += (size_t)Rp * 4;
    int*   tok_e      = (int*)(ws + o);   o += (size_t)2 * T * 4;
    float* tok_w      = (float*)(ws + o); o += (size_t)2 * T * 4;
    int*   tok_pos    = (int*)(ws + o);   o += (size_t)2 * T * 4;
    int*   counts     = (int*)(ws + o);   o += 16 * 4;
    int*   offs       = (int*)(ws + o);   o += 16 * 4;

    // y aliases w13t (dead after gemm1)
    unsigned short* y = w13t;

    hipMemsetAsync(counts, 0, 16 * 4, stream);
    hipMemsetAsync(row_token, 0, (size_t)Rp * 4, stream);
    hipMemsetAsync(row_weight, 0, (size_t)Rp * 4, stream);

    const int nrouter = (T + 3) / 4;            // 1024
    const int nprep = nrouter + 6144;           // + transpose blocks ([64r][128c] tiles)
    k_prep<<<nprep, 256, 0, stream>>>(x, wr, w1, w3, w2, xb, w13t, w2t,
                                      tok_e, tok_w, counts, T, nrouter);

    k_scan_scatter<<<1, 1024, 0, stream>>>(counts, tok_e, tok_w, offs,
                                           row_token, row_weight, tok_pos, T);

    k_gemm1<<<G1X, 256, 0, stream>>>(xb, w13t, row_token, row_weight, offs, h);
    k_gemm2<<<G2X, 256, 0, stream>>>(h, w2t, offs, y);

    int n8 = T * D_MODEL / 8;
    k_combine<<<(n8 + 255) / 256, 256, 0, stream>>>(y, tok_pos, out, n8);
}

// Round 18
// 298.282 us; speedup vs baseline: 1.7426x; 1.0226x over previous
//
#include <hip/hip_runtime.h>
#include <stdint.h>

#define D_MODEL 1024
#define N_EXP   8
#define HIDDEN  2048
#define TOPK    2

#define BK    32
#define PADM  128
#define NT1   (D_MODEL / BK)   // 32
#define NT2   (HIDDEN / BK)    // 64
#define G1X   1152             // gemm-role blocks
#define G1W2  2048             // w2-transpose overlay blocks
#define G1TOT (G1X + G1W2)
#define G2X   288

typedef short bf16x8 __attribute__((ext_vector_type(8)));
typedef float f32x4 __attribute__((ext_vector_type(4)));
typedef unsigned u32x4 __attribute__((ext_vector_type(4)));

__device__ __forceinline__ unsigned short f2bf(float f) {
    union { float f; unsigned u; } v; v.f = f;
    unsigned r = v.u + 0x7fffu + ((v.u >> 16) & 1u);
    return (unsigned short)(r >> 16);
}

__device__ __forceinline__ float bf2f(unsigned short u) {
    union { unsigned u; float f; } v; v.u = (unsigned)u << 16; return v.f;
}

__device__ __forceinline__ void gload_lds16(const void* g, void* l) {
    __builtin_amdgcn_global_load_lds(
        (const __attribute__((address_space(1))) void*)g,
        (__attribute__((address_space(3))) void*)l, 16, 0, 0);
}

// ---------------- fused prep: router + x->bf16 AND w1/w3 transpose ----------------
__global__ __launch_bounds__(256) void k_prep(
    const float* __restrict__ x, const float* __restrict__ wr,
    const float* __restrict__ w1, const float* __restrict__ w3,
    unsigned short* __restrict__ xb,
    unsigned short* __restrict__ w13t,
    int* __restrict__ tok_e, float* __restrict__ tok_w,
    int* __restrict__ counts, int T, int nrouter)
{
    __shared__ unsigned tls[128][32];     // 16 KB
    const int bx = blockIdx.x;
    const int tid = threadIdx.x;

    if (bx < nrouter) {
        int t = bx * 4 + (tid >> 6);
        int lane = tid & 63;
        if (t >= T) return;
        const float4* xr = (const float4*)(x + (size_t)t * D_MODEL);
        float acc[N_EXP];
#pragma unroll
        for (int e = 0; e < N_EXP; ++e) acc[e] = 0.f;
#pragma unroll
        for (int j = 0; j < 4; ++j) {
            int c = j * 64 + lane;
            float4 v = xr[c];
            ushort4 pk;
            pk.x = f2bf(v.x); pk.y = f2bf(v.y); pk.z = f2bf(v.z); pk.w = f2bf(v.w);
            *(ushort4*)(xb + (size_t)t * D_MODEL + c * 4) = pk;
            const float4* w4 = (const float4*)(wr + (size_t)c * 4 * N_EXP);
#pragma unroll
            for (int k = 0; k < 4; ++k) {
                float xv = (k == 0) ? v.x : (k == 1) ? v.y : (k == 2) ? v.z : v.w;
                float4 wa = w4[k * 2], wb = w4[k * 2 + 1];
                acc[0] += xv * wa.x; acc[1] += xv * wa.y; acc[2] += xv * wa.z; acc[3] += xv * wa.w;
                acc[4] += xv * wb.x; acc[5] += xv * wb.y; acc[6] += xv * wb.z; acc[7] += xv * wb.w;
            }
        }
#pragma unroll
        for (int off = 32; off > 0; off >>= 1) {
#pragma unroll
            for (int e = 0; e < N_EXP; ++e) acc[e] += __shfl_down(acc[e], off, 64);
        }
        if (lane == 0) {
            float mx = acc[0];
#pragma unroll
            for (int e = 1; e < N_EXP; ++e) mx = fmaxf(mx, acc[e]);
            float p[N_EXP], den = 0.f;
#pragma unroll
            for (int e = 0; e < N_EXP; ++e) { p[e] = __expf(acc[e] - mx); den += p[e]; }
            float inv = 1.f / den;
            int e0 = 0; float v0 = acc[0];
#pragma unroll
            for (int e = 1; e < N_EXP; ++e) if (acc[e] > v0) { v0 = acc[e]; e0 = e; }
            int e1 = -1; float v1 = -1e30f;
#pragma unroll
            for (int e = 0; e < N_EXP; ++e) if (e != e0 && acc[e] > v1) { v1 = acc[e]; e1 = e; }
            tok_e[2 * t] = e0;     tok_w[2 * t] = p[e0] * inv;
            tok_e[2 * t + 1] = e1; tok_w[2 * t + 1] = p[e1] * inv;
            atomicAdd(&counts[e0], 1);
            atomicAdd(&counts[e1], 1);
        }
        return;
    }

    // ---- w1/w3 convert + transpose + interleave, [64 r][128 c] tile ----
    const int b2 = bx - nrouter;          // 0..4095
    const int z = b2 >> 8;                // 0..15
    const int inner = b2 & 255;
    const int mat = z >> 3, e = z & 7;
    const float* in = mat ? w3 : w1;
    const int Cc = HIDDEN;
    const size_t eb_in = (size_t)e * D_MODEL * HIDDEN;
    const int ntc = HIDDEN >> 7;          // 16
    const int c0 = (inner % ntc) * 128;
    const int r0 = (inner / ntc) * 64;

    const int c4 = tid & 31;
    const int rbase = tid >> 5;           // 0..7
    float4 v[8];
#pragma unroll
    for (int p = 0; p < 8; ++p) {
        int row = p * 8 + rbase;
        v[p] = *(const float4*)(in + eb_in + (size_t)(r0 + row) * Cc + c0 + c4 * 4);
    }
    const unsigned swz = (unsigned)((c4 & 7) << 2);
#pragma unroll
    for (int p = 0; p < 8; ++p) {
        int row = p * 8 + rbase;
        unsigned x01 = (unsigned)f2bf(v[p].x) | ((unsigned)f2bf(v[p].y) << 16);
        unsigned x23 = (unsigned)f2bf(v[p].z) | ((unsigned)f2bf(v[p].w) << 16);
        unsigned p01 = __shfl_xor(x01, 32, 64);
        unsigned p23 = __shfl_xor(x23, 32, 64);
        int rr = row >> 1;
        unsigned col = (unsigned)rr ^ swz;
        if ((row & 1) == 0) {
            tls[c4 * 4 + 0][col] = (x01 & 0xffffu) | (p01 << 16);
            tls[c4 * 4 + 1][col] = (x01 >> 16) | (p01 & 0xffff0000u);
        } else {
            tls[c4 * 4 + 2][col] = (p23 & 0xffffu) | (x23 << 16);
            tls[c4 * 4 + 3][col] = (p23 >> 16) | (x23 & 0xffff0000u);
        }
    }
    __syncthreads();

    const size_t eb = (size_t)e * (2 * HIDDEN) * D_MODEL;
    const int moff = mat ? 16 : 0;
#pragma unroll
    for (int p = 0; p < 4; ++p) {
        int li = p * 256 + tid;
        int c = li >> 3;
        int j = li & 7;
        unsigned s2 = (unsigned)(((c >> 2) & 7) << 2);
        u32x4 d = *(const u32x4*)(&tls[c][(unsigned)(j * 4) ^ s2]);
        int C = c0 + c;
        int r13 = ((C >> 4) << 5) + moff + (C & 15);
        *(u32x4*)(&w13t[eb + (size_t)r13 * D_MODEL + r0 + j * 8]) = d;
    }
}

// ---------------- scan (padded to PADM) + scatter, single block ----------------
__global__ void k_scan_scatter(const int* __restrict__ counts,
                               const int* __restrict__ tok_e, const float* __restrict__ tok_w,
                               int* __restrict__ offs,
                               int* __restrict__ row_token, float* __restrict__ row_weight,
                               int* __restrict__ tok_pos, int T) {
    __shared__ int scurs[N_EXP];
    if (threadIdx.x == 0) {
        int s = 0;
        for (int e = 0; e < N_EXP; ++e) {
            offs[e] = s; scurs[e] = s;
            s += ((counts[e] + PADM - 1) / PADM) * PADM;
        }
        offs[N_EXP] = s;
    }
    __syncthreads();
    for (int i = threadIdx.x; i < 2 * T; i += blockDim.x) {
        int e = tok_e[i];
        int pos = atomicAdd(&scurs[e], 1);
        row_token[pos] = i >> 1;
        row_weight[pos] = tok_w[i];
        tok_pos[i] = pos;
    }
}

// ---------------- GEMM1 (+ w2-transpose overlay): 128m x 256n, BK=32, 3-buf d2 ----------------
__global__ __launch_bounds__(256, 2) void k_gemm1(
    const unsigned short* __restrict__ xb,    // [T][D] bf16
    const unsigned short* __restrict__ w13t,  // [E][2H][D] bf16 interleaved
    const float* __restrict__ w2,             // [E][H][D] f32 (overlay input)
    unsigned short* __restrict__ w2t,         // [E][D][H] bf16 (overlay output)
    const int* __restrict__ row_token,
    const float* __restrict__ row_weight,
    const int* __restrict__ offs,             // [E+1] 128-padded
    unsigned short* __restrict__ h)           // [Rp][H] bf16
{
    __shared__ unsigned short A[3][128 * BK];   // 3 x 8 KB
    __shared__ unsigned short B[3][256 * BK];   // 3 x 16 KB

    const int bxx = blockIdx.x;
    const int tid = threadIdx.x;

    if (bxx >= G1X) {
        // ---- w2 convert+transpose overlay (memory-bound, backfills gemm tail) ----
        const int b2 = bxx - G1X;            // 0..2047
        const int e2 = b2 >> 8, inner = b2 & 255;
        const size_t eb_in = (size_t)e2 * HIDDEN * D_MODEL;
        const int c0 = (inner & 7) * 128;    // D: 8 c-tiles
        const int r0 = (inner >> 3) * 64;    // H: 32 r-tiles
        unsigned (*tls)[32] = (unsigned(*)[32])&A[0][0];   // 16 KB scratch

        const int c4 = tid & 31;
        const int rbase = tid >> 5;
        float4 v[8];
#pragma unroll
        for (int p = 0; p < 8; ++p) {
            int row = p * 8 + rbase;
            v[p] = *(const float4*)(w2 + eb_in + (size_t)(r0 + row) * D_MODEL + c0 + c4 * 4);
        }
        const unsigned swz = (unsigned)((c4 & 7) << 2);
#pragma unroll
        for (int p = 0; p < 8; ++p) {
            int row = p * 8 + rbase;
            unsigned x01 = (unsigned)f2bf(v[p].x) | ((unsigned)f2bf(v[p].y) << 16);
            unsigned x23 = (unsigned)f2bf(v[p].z) | ((unsigned)f2bf(v[p].w) << 16);
            unsigned p01 = __shfl_xor(x01, 32, 64);
            unsigned p23 = __shfl_xor(x23, 32, 64);
            int rr = row >> 1;
            unsigned col = (unsigned)rr ^ swz;
            if ((row & 1) == 0) {
                tls[c4 * 4 + 0][col] = (x01 & 0xffffu) | (p01 << 16);
                tls[c4 * 4 + 1][col] = (x01 >> 16) | (p01 & 0xffff0000u);
            } else {
                tls[c4 * 4 + 2][col] = (p23 & 0xffffu) | (x23 << 16);
                tls[c4 * 4 + 3][col] = (p23 >> 16) | (x23 & 0xffff0000u);
            }
        }
        __syncthreads();
        const size_t eb = (size_t)e2 * D_MODEL * HIDDEN;
#pragma unroll
        for (int p = 0; p < 4; ++p) {
            int li = p * 256 + tid;
            int c = li >> 3;
            int j = li & 7;
            unsigned s2 = (unsigned)(((c >> 2) & 7) << 2);
            u32x4 d = *(const u32x4*)(&tls[c][(unsigned)(j * 4) ^ s2]);
            *(u32x4*)(&w2t[eb + (size_t)(c0 + c) * HIDDEN + r0 + j * 8]) = d;
        }
        return;
    }

    // ---- gemm role (R17-exact) ----
    const int b = bxx;
    const int bs = (b & 7) * (G1X / 8) + (b >> 3);
    int e = 0, mt = 0, nt = 0, found = 0, at = 0;
#pragma unroll
    for (int ee = 0; ee < N_EXP; ++ee) {
        int me = (offs[ee + 1] - offs[ee]) >> 7;
        int te = me * 16;
        if (!found && bs < at + te) {
            int loc = bs - at;
            nt = loc / me;
            mt = loc - nt * me;
            e = ee; found = 1;
        }
        at += te;
    }
    if (!found) return;
    const int m0 = offs[e] + mt * 128;
    const int n0b = nt * 256;

    const int lane = tid & 63, wn = tid >> 6;   // 4 waves, 1M x 4N

    const unsigned short* asrc[2];
    unsigned aoff[2];
#pragma unroll
    for (int q = 0; q < 2; ++q) {
        int c = q * 256 + tid;
        int m = c >> 2, kc = c & 3;
        int kcs = kc ^ (m & 3);
        int tok = row_token[m0 + m];
        asrc[q] = xb + (size_t)tok * D_MODEL + kcs * 8;
        aoff[q] = (unsigned)c * 8u;
    }
    const unsigned short* bsrc[4];
    unsigned boff[4];
#pragma unroll
    for (int q = 0; q < 4; ++q) {
        int c = q * 256 + tid;
        int n = c >> 2, kc = c & 3;
        int kcs = kc ^ (n & 3);
        bsrc[q] = w13t + ((size_t)e * (2 * HIDDEN) + n0b + n) * D_MODEL + kcs * 8;
        boff[q] = (unsigned)c * 8u;
    }

    f32x4 acc[8][4];
    const f32x4 zf = {0.f, 0.f, 0.f, 0.f};
#pragma unroll
    for (int mi = 0; mi < 8; ++mi)
#pragma unroll
        for (int ni = 0; ni < 4; ++ni) acc[mi][ni] = zf;

#pragma unroll
    for (int t = 0; t < 2; ++t) {
        const int ko = t * BK;
        gload_lds16(asrc[0] + ko, &A[t][aoff[0]]);
        gload_lds16(asrc[1] + ko, &A[t][aoff[1]]);
        gload_lds16(bsrc[0] + ko, &B[t][boff[0]]);
        gload_lds16(bsrc[1] + ko, &B[t][boff[1]]);
        gload_lds16(bsrc[2] + ko, &B[t][boff[2]]);
        gload_lds16(bsrc[3] + ko, &B[t][boff[3]]);
    }

    int cur = 0;
#pragma unroll 1
    for (int kt = 0; kt < NT1; ++kt) {
        if (kt == NT1 - 1) asm volatile("s_waitcnt vmcnt(0)" ::: "memory");
        else               asm volatile("s_waitcnt vmcnt(6)" ::: "memory");
        __builtin_amdgcn_s_barrier();

        const unsigned short* Ac = &A[cur][0];
        const unsigned short* Bc = &B[cur][0];
        const int nb = (cur + 2 >= 3) ? (cur - 1) : (cur + 2);
        const int ko = (kt + 2) * BK;
        const bool pf = (kt + 2 < NT1);

        bf16x8 a[8], bf[4];
        const int ke = (lane >> 4) * 8;
#pragma unroll
        for (int mi = 0; mi < 8; ++mi) {
            int m = mi * 16 + (lane & 15);
            a[mi] = *(const bf16x8*)(&Ac[m * BK + (ke ^ ((m & 3) * 8))]);
        }
#pragma unroll
        for (int ni = 0; ni < 4; ++ni) {
            int n = wn * 64 + ni * 16 + (lane & 15);
            bf[ni] = *(const bf16x8*)(&Bc[n * BK + (ke ^ ((n & 3) * 8))]);
        }
        if (pf) {
            gload_lds16(asrc[0] + ko, &A[nb][aoff[0]]);
            gload_lds16(asrc[1] + ko, &A[nb][aoff[1]]);
            gload_lds16(bsrc[0] + ko, &B[nb][boff[0]]);
            gload_lds16(bsrc[1] + ko, &B[nb][boff[1]]);
            gload_lds16(bsrc[2] + ko, &B[nb][boff[2]]);
            gload_lds16(bsrc[3] + ko, &B[nb][boff[3]]);
        }
        __builtin_amdgcn_s_barrier();
        __builtin_amdgcn_s_setprio(1);
#pragma unroll
        for (int mi = 0; mi < 8; ++mi)
#pragma unroll
            for (int ni = 0; ni < 4; ++ni)
                acc[mi][ni] = __builtin_amdgcn_mfma_f32_16x16x32_bf16(a[mi], bf[ni], acc[mi][ni], 0, 0, 0);
        __builtin_amdgcn_s_setprio(0);
        cur = (cur == 2) ? 0 : (cur + 1);
    }

    const int g0 = (n0b + wn * 64) >> 5;
#pragma unroll
    for (int mi = 0; mi < 8; ++mi) {
#pragma unroll
        for (int r = 0; r < 4; ++r) {
            int m = mi * 16 + (lane >> 4) * 4 + r;
            float wgt = row_weight[m0 + m];
            size_t rowbase = (size_t)(m0 + m) * HIDDEN;
#pragma unroll
            for (int p = 0; p < 2; ++p) {
                float v1 = acc[mi][2 * p][r], v3 = acc[mi][2 * p + 1][r];
                float sv = v1 / (1.f + __expf(-v1));
                int hc = (g0 + p) * 16 + (lane & 15);
                h[rowbase + hc] = f2bf(sv * v3 * wgt);
            }
        }
    }
}

// ---------------- GEMM2: 128m x 256n, BK=32, 3-buf d2 (R17-exact) ----------------
__global__ __launch_bounds__(256, 2) void k_gemm2(
    const unsigned short* __restrict__ hh,   // [Rp][H] bf16
    const unsigned short* __restrict__ w2t,  // [E][D][H] bf16
    const int* __restrict__ offs,
    unsigned short* __restrict__ y)          // [Rp][D] bf16
{
    __shared__ unsigned short A[3][128 * BK];
    __shared__ unsigned short B[3][256 * BK];

    const int b = blockIdx.x;
    const int bs = (b & 7) * (G2X / 8) + (b >> 3);
    int e = 0, mt = 0, nt = 0, found = 0, at = 0;
#pragma unroll
    for (int ee = 0; ee < N_EXP; ++ee) {
        int me = (offs[ee + 1] - offs[ee]) >> 7;
        int te = me * 4;
        if (!found && bs < at + te) {
            int loc = bs - at;
            nt = loc / me;
            mt = loc - nt * me;
            e = ee; found = 1;
        }
        at += te;
    }
    if (!found) return;
    const int m0 = offs[e] + mt * 128;
    const int n0 = nt * 256;

    const int tid = threadIdx.x;
    const int lane = tid & 63, wn = tid >> 6;

    const unsigned short* asrc[2];
    unsigned aoff[2];
#pragma unroll
    for (int q = 0; q < 2; ++q) {
        int c = q * 256 + tid;
        int m = c >> 2, kc = c & 3;
        int kcs = kc ^ (m & 3);
        asrc[q] = hh + (size_t)(m0 + m) * HIDDEN + kcs * 8;
        aoff[q] = (unsigned)c * 8u;
    }
    const unsigned short* bsrc[4];
    unsigned boff[4];
#pragma unroll
    for (int q = 0; q < 4; ++q) {
        int c = q * 256 + tid;
        int n = c >> 2, kc = c & 3;
        int kcs = kc ^ (n & 3);
        bsrc[q] = w2t + ((size_t)e * D_MODEL + n0 + n) * HIDDEN + kcs * 8;
        boff[q] = (unsigned)c * 8u;
    }

    f32x4 acc[8][4];
    const f32x4 zf = {0.f, 0.f, 0.f, 0.f};
#pragma unroll
    for (int mi = 0; mi < 8; ++mi)
#pragma unroll
        for (int ni = 0; ni < 4; ++ni) acc[mi][ni] = zf;

#pragma unroll
    for (int t = 0; t < 2; ++t) {
        const int ko = t * BK;
        gload_lds16(asrc[0] + ko, &A[t][aoff[0]]);
        gload_lds16(asrc[1] + ko, &A[t][aoff[1]]);
        gload_lds16(bsrc[0] + ko, &B[t][boff[0]]);
        gload_lds16(bsrc[1] + ko, &B[t][boff[1]]);
        gload_lds16(bsrc[2] + ko, &B[t][boff[2]]);
        gload_lds16(bsrc[3] + ko, &B[t][boff[3]]);
    }

    int cur = 0;
#pragma unroll 1
    for (int kt = 0; kt < NT2; ++kt) {
        if (kt == NT2 - 1) asm volatile("s_waitcnt vmcnt(0)" ::: "memory");
        else               asm volatile("s_waitcnt vmcnt(6)" ::: "memory");
        __builtin_amdgcn_s_barrier();

        const unsigned short* Ac = &A[cur][0];
        const unsigned short* Bc = &B[cur][0];
        const int nb = (cur + 2 >= 3) ? (cur - 1) : (cur + 2);
        const int ko = (kt + 2) * BK;
        const bool pf = (kt + 2 < NT2);

        bf16x8 a[8], bf[4];
        const int ke = (lane >> 4) * 8;
#pragma unroll
        for (int mi = 0; mi < 8; ++mi) {
            int m = mi * 16 + (lane & 15);
            a[mi] = *(const bf16x8*)(&Ac[m * BK + (ke ^ ((m & 3) * 8))]);
        }
#pragma unroll
        for (int ni = 0; ni < 4; ++ni) {
            int n = wn * 64 + ni * 16 + (lane & 15);
            bf[ni] = *(const bf16x8*)(&Bc[n * BK + (ke ^ ((n & 3) * 8))]);
        }
        if (pf) {
            gload_lds16(asrc[0] + ko, &A[nb][aoff[0]]);
            gload_lds16(asrc[1] + ko, &A[nb][aoff[1]]);
            gload_lds16(bsrc[0] + ko, &B[nb][boff[0]]);
            gload_lds16(bsrc[1] + ko, &B[nb][boff[1]]);
            gload_lds16(bsrc[2] + ko, &B[nb][boff[2]]);
            gload_lds16(bsrc[3] + ko, &B[nb][boff[3]]);
        }
        __builtin_amdgcn_s_barrier();
        __builtin_amdgcn_s_setprio(1);
#pragma unroll
        for (int mi = 0; mi < 8; ++mi)
#pragma unroll
            for (int ni = 0; ni < 4; ++ni)
                acc[mi][ni] = __builtin_amdgcn_mfma_f32_16x16x32_bf16(a[mi], bf[ni], acc[mi][ni], 0, 0, 0);
        __builtin_amdgcn_s_setprio(0);
        cur = (cur == 2) ? 0 : (cur + 1);
    }

#pragma unroll
    for (int mi = 0; mi < 8; ++mi) {
#pragma unroll
        for (int r = 0; r < 4; ++r) {
            int m = mi * 16 + (lane >> 4) * 4 + r;
            size_t rowbase = (size_t)(m0 + m) * D_MODEL + n0;
#pragma unroll
            for (int ni = 0; ni < 4; ++ni) {
                int n = wn * 64 + ni * 16 + (lane & 15);
                y[rowbase + n] = f2bf(acc[mi][ni][r]);
            }
        }
    }
}

// ---------------- combine: out[t] = y[pos0] + y[pos1] ----------------
__global__ void k_combine(const unsigned short* __restrict__ y,
                          const int* __restrict__ tok_pos,
                          float* __restrict__ out, int n8) {
    int i = blockIdx.x * blockDim.x + threadIdx.x;
    if (i >= n8) return;
    int t = i >> 7;
    int c = (i & 127) * 8;
    int p0 = tok_pos[2 * t];
    int p1 = tok_pos[2 * t + 1];
    bf16x8 v0 = *(const bf16x8*)(y + (size_t)p0 * D_MODEL + c);
    bf16x8 v1 = *(const bf16x8*)(y + (size_t)p1 * D_MODEL + c);
    float* op = out + (size_t)t * D_MODEL + c;
    float4 o0, o1;
    o0.x = bf2f((unsigned short)v0[0]) + bf2f((unsigned short)v1[0]);
    o0.y = bf2f((unsigned short)v0[1]) + bf2f((unsigned short)v1[1]);
    o0.z = bf2f((unsigned short)v0[2]) + bf2f((unsigned short)v1[2]);
    o0.w = bf2f((unsigned short)v0[3]) + bf2f((unsigned short)v1[3]);
    o1.x = bf2f((unsigned short)v0[4]) + bf2f((unsigned short)v1[4]);
    o1.y = bf2f((unsigned short)v0[5]) + bf2f((unsigned short)v1[5]);
    o1.z = bf2f((unsigned short)v0[6]) + bf2f((unsigned short)v1[6]);
    o1.w = bf2f((unsigned short)v0[7]) + bf2f((unsigned short)v1[7]);
    *(float4*)op = o0;
    *(float4*)(op + 4) = o1;
}

extern "C" void kernel_launch(void* const* d_in, const int* in_sizes, int n_in,
                              void* d_out, int out_size, void* d_ws, size_t ws_size,
                              hipStream_t stream) {
    const float* x  = (const float*)d_in[0];
    const float* wr = (const float*)d_in[1];
    const float* w1 = (const float*)d_in[2];
    const float* w3 = (const float*)d_in[3];
    const float* w2 = (const float*)d_in[4];
    float* out = (float*)d_out;

    const int T = in_sizes[0] / D_MODEL;    // 4096
    const int Rp = T * TOPK + N_EXP * PADM; // 9216

    char* ws = (char*)d_ws;
    size_t o = 0;
    unsigned short* xb   = (unsigned short*)(ws + o); o += (size_t)T * D_MODEL * 2;
    unsigned short* h    = (unsigned short*)(ws + o); o += (size_t)Rp * HIDDEN * 2;
    unsigned short* w13t = (unsigned short*)(ws + o); o += (size_t)N_EXP * 2 * HIDDEN * D_MODEL * 2;
    unsigned short* w2t  = (unsigned short*)(ws + o); o += (size_t)N_EXP * D_MODEL * HIDDEN * 2;
    int*   row_token  = (int*)(ws + o);   o += (size_t)Rp * 4;
    float* row_weight = (float*)(ws + o); o += (size_t)Rp * 4;
    int*   tok_e      = (int*)(ws + o);   o += (size_t)2 * T * 4;
    float* tok_w      = (float*)(ws + o); o += (size_t)2 * T * 4;
    int*   tok_pos    = (int*)(ws + o);   o += (size_t)2 * T * 4;
    int*   counts     = (int*)(ws + o);   o += 16 * 4;
    int*   offs       = (int*)(ws + o);   o += 16 * 4;

    // y aliases w13t (dead after gemm1)
    unsigned short* y = w13t;

    hipMemsetAsync(counts, 0, 16 * 4, stream);
    hipMemsetAsync(row_token, 0, (size_t)Rp * 4, stream);
    hipMemsetAsync(row_weight, 0, (size_t)Rp * 4, stream);

    const int nrouter = (T + 3) / 4;            // 1024
    const int nprep = nrouter + 4096;           // + w1/w3 transpose blocks
    k_prep<<<nprep, 256, 0, stream>>>(x, wr, w1, w3, xb, w13t,
                                      tok_e, tok_w, counts, T, nrouter);

    k_scan_scatter<<<1, 1024, 0, stream>>>(counts, tok_e, tok_w, offs,
                                           row_token, row_weight, tok_pos, T);

    k_gemm1<<<G1TOT, 256, 0, stream>>>(xb, w13t, w2, w2t, row_token, row_weight, offs, h);
    k_gemm2<<<G2X, 256, 0, stream>>>(h, w2t, offs, y);

    int n8 = T * D_MODEL / 8;
    k_combine<<<(n8 + 255) / 256, 256, 0, stream>>>(y, tok_pos, out, n8);
}